// Round 7
// baseline (241.378 us; speedup 1.0000x reference)
//
#include <hip/hip_runtime.h>
#include <hip/hip_fp16.h>

#define NV 8
#define NQ 4096
#define C_ 256
#define HEADS 8
#define PTS 4
#define HV 23
#define WV 46
#define NPIX (HV*WV)       // 1058
#define BS 8
#define NROW (BS*NQ)       // 32768
#define NVBLK2 ((BS*NPIX)/16) // 529 value blocks (16 rows each)
#define NQBLK (NROW/16)       // 2048 query blocks

typedef unsigned short ushort_t;
typedef unsigned int uint_t;

// ---------------- prep (65 blocks): 0..63 WvWout = Wv@Wout; 64: wp2f = Wout@Wp, bvW = bv@Wout, cnt=0 ----------------
__global__ void prep_kernel(const float* __restrict__ Wout, const float* __restrict__ Wp,
                            const float* __restrict__ Wv, const float* __restrict__ bv,
                            float* __restrict__ WvWout, float* __restrict__ wp2f,
                            float* __restrict__ bvW, int* __restrict__ cnt) {
    int blk = blockIdx.x;
    int t = threadIdx.x;
    __shared__ float rows[4][C_];
    if (blk < 64) {
        int r0 = blk * 4;
        #pragma unroll
        for (int r = 0; r < 4; ++r) rows[r][t] = Wv[(r0 + r) * C_ + t];
        __syncthreads();
        float acc[4] = {0.f, 0.f, 0.f, 0.f};
        for (int k = 0; k < C_; ++k) {
            float w = Wout[k * C_ + t];
            acc[0] = fmaf(rows[0][k], w, acc[0]);
            acc[1] = fmaf(rows[1][k], w, acc[1]);
            acc[2] = fmaf(rows[2][k], w, acc[2]);
            acc[3] = fmaf(rows[3][k], w, acc[3]);
        }
        #pragma unroll
        for (int r = 0; r < 4; ++r) WvWout[(r0 + r) * C_ + t] = acc[r];
    } else {
        if (t == 0) *cnt = 0;
        float a = 0.f;
        for (int c = 0; c < C_; ++c) a = fmaf(Wout[t * C_ + c], Wp[c], a);
        wp2f[t] = a;
        float fb = 0.f;
        for (int d = 0; d < C_; ++d) fb = fmaf(bv[d], Wout[d * C_ + t], fb);
        bvW[t] = fb;
    }
}

// ---------------- proj_val (529 blocks): 8-rows x 2-cols per thread; half the ds_reads of R2 ----------------
// col pair = (t&127, t&127+128); rows = (t>>7)*8 .. +8. All ds_reads wave-uniform broadcast.
// Per-(row,col) fma chains sequential-k, identical to R2 -> v2d/VW/S32 bit-identical.
__global__ void __launch_bounds__(256) proj_val_kernel(
        const float* __restrict__ value, const float* __restrict__ Wv,
        const float* __restrict__ bv, const float* __restrict__ WvWout,
        const float* __restrict__ bvW, const float* __restrict__ wp2f,
        float* __restrict__ v2d, ushort_t* __restrict__ VW,
        float* __restrict__ S32) {
#pragma clang fp contract(off)
    __shared__ float rows[16][C_];
    int blk = blockIdx.x;
    int t = threadIdx.x;
    int r0 = blk * 16;
    #pragma unroll
    for (int i = 0; i < 16; ++i) {
        int idx = t + i * 256;
        rows[idx >> 8][idx & 255] = value[(size_t)r0 * C_ + idx];
    }
    __syncthreads();
    int c = t & 127, rg = t >> 7;         // rows rg*8 .. rg*8+7
    float acc0[8], acc1[8], accW0[8], accW1[8];
    #pragma unroll
    for (int i = 0; i < 8; ++i) { acc0[i] = 0.f; acc1[i] = 0.f; accW0[i] = 0.f; accW1[i] = 0.f; }
    for (int k4 = 0; k4 < C_ / 4; ++k4) {
        int k = k4 * 4;
        float wa0 = Wv[(k + 0) * C_ + c], wa1 = Wv[(k + 1) * C_ + c];
        float wa2 = Wv[(k + 2) * C_ + c], wa3 = Wv[(k + 3) * C_ + c];
        float wb0 = Wv[(k + 0) * C_ + c + 128], wb1 = Wv[(k + 1) * C_ + c + 128];
        float wb2 = Wv[(k + 2) * C_ + c + 128], wb3 = Wv[(k + 3) * C_ + c + 128];
        float ua0 = WvWout[(k + 0) * C_ + c], ua1 = WvWout[(k + 1) * C_ + c];
        float ua2 = WvWout[(k + 2) * C_ + c], ua3 = WvWout[(k + 3) * C_ + c];
        float ub0 = WvWout[(k + 0) * C_ + c + 128], ub1 = WvWout[(k + 1) * C_ + c + 128];
        float ub2 = WvWout[(k + 2) * C_ + c + 128], ub3 = WvWout[(k + 3) * C_ + c + 128];
        #pragma unroll
        for (int i = 0; i < 8; ++i) {
            const float4 qv = *(reinterpret_cast<const float4*>(rows[rg * 8 + i]) + k4);
            acc0[i] = __builtin_fmaf(qv.x, wa0, acc0[i]);   // exact: sequential k order
            acc0[i] = __builtin_fmaf(qv.y, wa1, acc0[i]);
            acc0[i] = __builtin_fmaf(qv.z, wa2, acc0[i]);
            acc0[i] = __builtin_fmaf(qv.w, wa3, acc0[i]);
            acc1[i] = __builtin_fmaf(qv.x, wb0, acc1[i]);
            acc1[i] = __builtin_fmaf(qv.y, wb1, acc1[i]);
            acc1[i] = __builtin_fmaf(qv.z, wb2, acc1[i]);
            acc1[i] = __builtin_fmaf(qv.w, wb3, acc1[i]);
            accW0[i] = fmaf(qv.x, ua0, accW0[i]);
            accW0[i] = fmaf(qv.y, ua1, accW0[i]);
            accW0[i] = fmaf(qv.z, ua2, accW0[i]);
            accW0[i] = fmaf(qv.w, ua3, accW0[i]);
            accW1[i] = fmaf(qv.x, ub0, accW1[i]);
            accW1[i] = fmaf(qv.y, ub1, accW1[i]);
            accW1[i] = fmaf(qv.z, ub2, accW1[i]);
            accW1[i] = fmaf(qv.w, ub3, accW1[i]);
        }
    }
    float b0 = bv[c], b1 = bv[c + 128];
    float g0 = bvW[c], g1 = bvW[c + 128];
    float wp0 = wp2f[c], wp1 = wp2f[c + 128];
    int h0 = c >> 5;                       // head of col c (0..3); col c+128 -> head h0+4
    #pragma unroll
    for (int i = 0; i < 8; ++i) {
        int row = r0 + rg * 8 + i;
        float vd0 = acc0[i] + b0;
        float vd1 = acc1[i] + b1;
        v2d[(size_t)row * C_ + c] = vd0;
        v2d[(size_t)row * C_ + c + 128] = vd1;
        VW[(size_t)row * C_ + c] = __half_as_ushort(__float2half(accW0[i] + g0));
        VW[(size_t)row * C_ + c + 128] = __half_as_ushort(__float2half(accW1[i] + g1));
        // S32: same (lane,col) partials and shfl tree as R2 -> bit-identical
        float p0 = vd0 * wp0;
        p0 += __shfl_down(p0, 16, 32);
        p0 += __shfl_down(p0, 8, 32);
        p0 += __shfl_down(p0, 4, 32);
        p0 += __shfl_down(p0, 2, 32);
        p0 += __shfl_down(p0, 1, 32);
        float p1 = vd1 * wp1;
        p1 += __shfl_down(p1, 16, 32);
        p1 += __shfl_down(p1, 8, 32);
        p1 += __shfl_down(p1, 4, 32);
        p1 += __shfl_down(p1, 2, 32);
        p1 += __shfl_down(p1, 1, 32);
        if ((t & 31) == 0) {
            S32[(size_t)row * HEADS + h0] = p0;
            S32[(size_t)row * HEADS + 4 + h0] = p1;
        }
    }
}

// ---------------- proj_qry (2048 blocks): 64 cols x 4 row-groups; Wa fused into cols<32 ----------------
// 4 ds_reads/iter (wave-uniform) vs R2's 8; zero idle lanes. offn/attn bit-identical.
__global__ void __launch_bounds__(256) proj_qry_kernel(
        const float* __restrict__ query,
        const float* __restrict__ Wo, const float* __restrict__ bo,
        const float* __restrict__ Wa, const float* __restrict__ ba,
        float* __restrict__ offn, float* __restrict__ attn) {
#pragma clang fp contract(off)
    __shared__ float qs[16][C_];
    __shared__ float lg[16][32];
    int qb = blockIdx.x;
    int t = threadIdx.x;
    int rb = qb * 16;
    #pragma unroll
    for (int i = 0; i < 16; ++i) {
        int idx = t + i * 256;
        qs[idx >> 8][idx & 255] = query[(size_t)rb * C_ + idx];
    }
    __syncthreads();
    int col = t & 63, rg = t >> 6;         // rows rg*4 .. rg*4+3
    bool hasA = (col < 32);
    float accO[4] = {0.f, 0.f, 0.f, 0.f};
    float accA[4] = {0.f, 0.f, 0.f, 0.f};
    for (int k4 = 0; k4 < C_ / 4; ++k4) {
        int k = k4 * 4;
        float w0 = Wo[(k + 0) * 64 + col], w1 = Wo[(k + 1) * 64 + col];
        float w2 = Wo[(k + 2) * 64 + col], w3 = Wo[(k + 3) * 64 + col];
        float a0 = 0.f, a1 = 0.f, a2 = 0.f, a3 = 0.f;
        if (hasA) {
            a0 = Wa[(k + 0) * 32 + col]; a1 = Wa[(k + 1) * 32 + col];
            a2 = Wa[(k + 2) * 32 + col]; a3 = Wa[(k + 3) * 32 + col];
        }
        #pragma unroll
        for (int i = 0; i < 4; ++i) {
            const float4 qv = *(reinterpret_cast<const float4*>(qs[rg * 4 + i]) + k4);
            accO[i] = __builtin_fmaf(qv.x, w0, accO[i]);
            accO[i] = __builtin_fmaf(qv.y, w1, accO[i]);
            accO[i] = __builtin_fmaf(qv.z, w2, accO[i]);
            accO[i] = __builtin_fmaf(qv.w, w3, accO[i]);
            accA[i] = __builtin_fmaf(qv.x, a0, accA[i]);
            accA[i] = __builtin_fmaf(qv.y, a1, accA[i]);
            accA[i] = __builtin_fmaf(qv.z, a2, accA[i]);
            accA[i] = __builtin_fmaf(qv.w, a3, accA[i]);
        }
    }
    {
        float b = bo[col];
        float nrm = (col & 1) ? 23.0f : 46.0f;
        #pragma unroll
        for (int i = 0; i < 4; ++i)
            offn[(size_t)(rb + rg * 4 + i) * 64 + col] = (accO[i] + b) / nrm;
    }
    if (hasA) {
        float b = ba[col];
        #pragma unroll
        for (int i = 0; i < 4; ++i) lg[rg * 4 + i][col] = accA[i] + b;
    }
    __syncthreads();
    if (t < 128) {
        int r = t >> 3, h = t & 7;
        float v0 = lg[r][h * 4 + 0], v1 = lg[r][h * 4 + 1];
        float v2 = lg[r][h * 4 + 2], v3 = lg[r][h * 4 + 3];
        float m = fmaxf(fmaxf(fmaxf(v0, v1), v2), v3);
        float e0 = expf(v0 - m), e1 = expf(v1 - m), e2 = expf(v2 - m), e3 = expf(v3 - m);
        float s = ((e0 + e1) + e2) + e3;
        attn[(size_t)(rb + r) * 32 + h * 4 + 0] = e0 / s;
        attn[(size_t)(rb + r) * 32 + h * 4 + 1] = e1 / s;
        attn[(size_t)(rb + r) * 32 + h * 4 + 2] = e2 / s;
        attn[(size_t)(rb + r) * 32 + h * 4 + 3] = e3 / s;
    }
}

// ---------------- fused: f32 gap-tested logits (S32) + hfma2 sampling; R0 plain LDS layout ----------------
__global__ void __launch_bounds__(256) fused_kernel(
        const ushort_t* __restrict__ VW, const float* __restrict__ offn,
        const float* __restrict__ attn, const float* __restrict__ grd_col,
        const float* __restrict__ grd_row, const float* __restrict__ S32,
        const float* __restrict__ query, const float* __restrict__ bout,
        float* __restrict__ out, float* __restrict__ amax_out,
        int* __restrict__ cnt, int* __restrict__ list) {
    int bid = blockIdx.x;
    int row = ((bid & 7) << 12) | (bid >> 3);   // XCD-bijective: batch <-> XCD affinity
    int b = row >> 12;
    int q = row & (NQ - 1);
    int t = threadIdx.x;
    __shared__ __align__(16) int   g_ip[256][4];
    __shared__ __align__(16) float g_w[256][4];
    __shared__ __align__(16) float red[NV][C_];
    __shared__ float logits_sh[NV];
    __shared__ float wf_sh[NV];

    // ---- phase A (f32): t = v*32 + (h*4+p)
    {
        int v = t >> 5, r = t & 31, h = r >> 2;
        const float2 off2 = ((const float2*)(offn + (size_t)row * 64))[r];
        float at = attn[(size_t)row * 32 + r];
        float refx = grd_col[q * NV + v];
        float refy = grd_row[q * NV + v];
        float lx = refx + off2.x;
        float ly = refy + off2.y;
        float x = lx * 46.0f - 0.5f;
        float y = ly * 23.0f - 0.5f;
        float x0f = floorf(x), y0f = floorf(y);
        float wx1 = x - x0f, wy1 = y - y0f;
        float wx0 = 1.0f - wx1, wy0 = 1.0f - wy1;
        int xi = (int)x0f, yi = (int)y0f;
        bool vx0 = (x0f >= 0.0f) && (x0f < 46.0f);
        bool vx1 = (x0f + 1.0f >= 0.0f) && (x0f + 1.0f < 46.0f);
        bool vy0 = (y0f >= 0.0f) && (y0f < 23.0f);
        bool vy1 = (y0f + 1.0f >= 0.0f) && (y0f + 1.0f < 23.0f);
        int xc0 = min(max(xi, 0), WV - 1), xc1 = min(max(xi + 1, 0), WV - 1);
        int yc0 = min(max(yi, 0), HV - 1), yc1 = min(max(yi + 1, 0), HV - 1);
        float w00 = (vx0 && vy0) ? wx0 * wy0 : 0.0f;
        float w10 = (vx1 && vy0) ? wx1 * wy0 : 0.0f;
        float w01 = (vx0 && vy1) ? wx0 * wy1 : 0.0f;
        float w11 = (vx1 && vy1) ? wx1 * wy1 : 0.0f;
        int ip00 = yc0 * WV + xc0, ip10 = yc0 * WV + xc1;
        int ip01 = yc1 * WV + xc0, ip11 = yc1 * WV + xc1;

        g_ip[t][0] = ip00 * (C_ * 2); g_ip[t][1] = ip10 * (C_ * 2);   // byte offsets
        g_ip[t][2] = ip01 * (C_ * 2); g_ip[t][3] = ip11 * (C_ * 2);
        g_w[t][0] = w00 * at;  g_w[t][1] = w10 * at;
        g_w[t][2] = w01 * at;  g_w[t][3] = w11 * at;

        const float* Sb = S32 + (size_t)b * NPIX * HEADS;
        float samp = w00 * Sb[ip00 * HEADS + h] + w10 * Sb[ip10 * HEADS + h]
                   + w01 * Sb[ip01 * HEADS + h] + w11 * Sb[ip11 * HEADS + h];
        float contrib = at * samp;
        #pragma unroll
        for (int s2 = 16; s2; s2 >>= 1) contrib += __shfl_down(contrib, s2, 32);
        if (r == 0) logits_sh[v] = contrib;
    }
    __syncthreads();                                   // barrier 1 (A -> B)

    // ---- lanes 0..7 (f32): argmax + gap test + softmax weights
    if (t < 8) {
        float m = logits_sh[0]; int am = 0;
        #pragma unroll
        for (int v2 = 1; v2 < NV; ++v2) {
            float lv = logits_sh[v2];
            if (lv > m) { m = lv; am = v2; }
        }
        float e = expf(logits_sh[t] - m);
        float ssum = e;
        ssum += __shfl_xor(ssum, 1, 8);
        ssum += __shfl_xor(ssum, 2, 8);
        ssum += __shfl_xor(ssum, 4, 8);
        wf_sh[t] = e / ssum;
        if (t == 0) {
            amax_out[row] = (float)am;
            float m2 = -1e30f;
            #pragma unroll
            for (int v2 = 0; v2 < NV; ++v2) {
                float lv = logits_sh[v2];
                if (v2 != am && lv > m2) m2 = lv;
            }
            float thr = 1e-4f * fmaxf(1.0f, fabsf(m));
            if ((m - m2) < thr) {
                int idx = atomicAdd(cnt, 1);
                list[idx] = row;
            }
        }
    }

    // ---- phase B: 8 groups x 32 threads; group g = v; 8 channels/thread; packed f16 FMA
    {
        int g = t >> 5, lt = t & 31;
        int c0 = lt * 8;
        int c2 = c0 * 2;               // channel byte offset
        int hb = lt >> 2;
        const char* vb = (const char*)(VW + (size_t)b * NPIX * C_);
        __half2 h01 = __float2half2_rn(0.f);
        __half2 h23 = h01, h45 = h01, h67 = h01;
        #pragma unroll
        for (int pp = 0; pp < 2; ++pp) {
            int e0 = g * 32 + hb * 4 + pp * 2;         // entry (v=g, h=hb, p=pp*2); +1 -> p+1
            const int4   ipA = *reinterpret_cast<const int4*>(g_ip[e0]);
            const float4 wA  = *reinterpret_cast<const float4*>(g_w[e0]);
            const int4   ipB = *reinterpret_cast<const int4*>(g_ip[e0 + 1]);
            const float4 wB  = *reinterpret_cast<const float4*>(g_w[e0 + 1]);
            const uint4 uA0 = *reinterpret_cast<const uint4*>(vb + (ipA.x + c2));
            const uint4 uA1 = *reinterpret_cast<const uint4*>(vb + (ipA.y + c2));
            const uint4 uA2 = *reinterpret_cast<const uint4*>(vb + (ipA.z + c2));
            const uint4 uA3 = *reinterpret_cast<const uint4*>(vb + (ipA.w + c2));
            const uint4 uB0 = *reinterpret_cast<const uint4*>(vb + (ipB.x + c2));
            const uint4 uB1 = *reinterpret_cast<const uint4*>(vb + (ipB.y + c2));
            const uint4 uB2 = *reinterpret_cast<const uint4*>(vb + (ipB.z + c2));
            const uint4 uB3 = *reinterpret_cast<const uint4*>(vb + (ipB.w + c2));
            #define CORNER(W, U) { \
                const __half2 wh = __float2half2_rn(W); \
                h01 = __hfma2(wh, *reinterpret_cast<const __half2*>(&U.x), h01); \
                h23 = __hfma2(wh, *reinterpret_cast<const __half2*>(&U.y), h23); \
                h45 = __hfma2(wh, *reinterpret_cast<const __half2*>(&U.z), h45); \
                h67 = __hfma2(wh, *reinterpret_cast<const __half2*>(&U.w), h67); }
            CORNER(wA.x, uA0)
            CORNER(wA.y, uA1)
            CORNER(wA.z, uA2)
            CORNER(wA.w, uA3)
            CORNER(wB.x, uB0)
            CORNER(wB.y, uB1)
            CORNER(wB.z, uB2)
            CORNER(wB.w, uB3)
            #undef CORNER
        }
        float a0 = __low2float(h01), a1 = __high2float(h01);
        float a2 = __low2float(h23), a3 = __high2float(h23);
        float a4 = __low2float(h45), a5 = __high2float(h45);
        float a6 = __low2float(h67), a7 = __high2float(h67);
        float4 s0v = {a0, a1, a2, a3}, s1v = {a4, a5, a6, a7};
        *reinterpret_cast<float4*>(&red[g][c0])     = s0v;
        *reinterpret_cast<float4*>(&red[g][c0 + 4]) = s1v;
    }
    __syncthreads();                                   // barrier 2 (B -> epilogue)
    float O = 0.f;
    #pragma unroll
    for (int g8 = 0; g8 < NV; ++g8) O = fmaf(wf_sh[g8], red[g8][t], O);
    out[(size_t)row * C_ + t] = O + bout[t] + 2.0f * query[(size_t)row * C_ + t];
}

// ---------------- exact replication (compacted: grid-stride over flagged list) ----------------
__global__ void __launch_bounds__(256) exact_kernel(
        const float* __restrict__ v2d, const float* __restrict__ offn,
        const float* __restrict__ attn, const float* __restrict__ grd_col,
        const float* __restrict__ grd_row, const float* __restrict__ Wout,
        const float* __restrict__ bout, const float* __restrict__ Wp,
        const float* __restrict__ bp, const float* __restrict__ query,
        const int* __restrict__ cnt, const int* __restrict__ list,
        float* __restrict__ amax_out) {
#pragma clang fp contract(off)
    int n = *cnt;
    int t = threadIdx.x;
    int h = t >> 5;
    __shared__ float s_off[64];
    __shared__ float s_attn[32];
    __shared__ float wp_lds[C_];
    __shared__ float out_l[NV][C_ + 1];
    __shared__ float bevs_l[NV][C_ + 1];
    __shared__ float lgs[NV];
    wp_lds[t] = Wp[t];

    for (int i = blockIdx.x; i < n; i += gridDim.x) {
        int row = list[i];
        int b = row >> 12;
        int q = row & (NQ - 1);
        if (t < 64)      s_off[t]       = offn[(size_t)row * 64 + t];
        else if (t < 96) s_attn[t - 64] = attn[(size_t)row * 32 + (t - 64)];
        __syncthreads();

        const float* vb = v2d + (size_t)b * NPIX * C_;
        #pragma unroll
        for (int v = 0; v < NV; ++v) {
            float refx = grd_col[q * NV + v];
            float refy = grd_row[q * NV + v];
            float acc = 0.0f;
            #pragma unroll
            for (int p = 0; p < PTS; ++p) {
                float lx = refx + s_off[h * 8 + p * 2 + 0];
                float ly = refy + s_off[h * 8 + p * 2 + 1];
                float x = lx * 46.0f - 0.5f;
                float y = ly * 23.0f - 0.5f;
                float x0f = floorf(x), y0f = floorf(y);
                float wx1 = x - x0f, wy1 = y - y0f;
                float wx0 = 1.0f - wx1, wy0 = 1.0f - wy1;
                int xi = (int)x0f, yi = (int)y0f;
                bool vx0 = (x0f >= 0.0f) && (x0f < 46.0f);
                bool vx1 = (x0f + 1.0f >= 0.0f) && (x0f + 1.0f < 46.0f);
                bool vy0 = (y0f >= 0.0f) && (y0f < 23.0f);
                bool vy1 = (y0f + 1.0f >= 0.0f) && (y0f + 1.0f < 23.0f);
                int xc0 = min(max(xi, 0), WV - 1), xc1 = min(max(xi + 1, 0), WV - 1);
                int yc0 = min(max(yi, 0), HV - 1), yc1 = min(max(yi + 1, 0), HV - 1);
                float g00 = (vx0 && vy0) ? vb[(yc0 * WV + xc0) * C_ + t] : 0.0f;
                float g10 = (vx1 && vy0) ? vb[(yc0 * WV + xc1) * C_ + t] : 0.0f;
                float g01 = (vx0 && vy1) ? vb[(yc1 * WV + xc0) * C_ + t] : 0.0f;
                float g11 = (vx1 && vy1) ? vb[(yc1 * WV + xc1) * C_ + t] : 0.0f;
                float t00 = g00 * (wx0 * wy0);
                float t10 = g10 * (wx1 * wy0);
                float t01 = g01 * (wx0 * wy1);
                float t11 = g11 * (wx1 * wy1);
                float samp = ((t00 + t10) + t01) + t11;
                float pr = s_attn[h * 4 + p] * samp;
                acc = acc + pr;
            }
            out_l[v][t] = acc;
        }
        __syncthreads();

        float bacc[NV];
        #pragma unroll
        for (int v = 0; v < NV; ++v) bacc[v] = 0.f;
        for (int i2 = 0; i2 < C_; ++i2) {
            float w_it = Wout[i2 * C_ + t];
            #pragma unroll
            for (int v = 0; v < NV; ++v) bacc[v] = __builtin_fmaf(out_l[v][i2], w_it, bacc[v]);
        }
        float bo_t = bout[t];
        float qv = query[(size_t)row * C_ + t];
        #pragma unroll
        for (int v = 0; v < NV; ++v) bevs_l[v][t] = (bacc[v] + bo_t) + qv;
        __syncthreads();

        if (t < NV) {
            float lv = 0.f;
            for (int c = 0; c < C_; ++c) lv = __builtin_fmaf(bevs_l[t][c], wp_lds[c], lv);
            lgs[t] = lv + bp[0];
        }
        __syncthreads();

        if (t == 0) {
            float l[NV];
            #pragma unroll
            for (int v = 0; v < NV; ++v) l[v] = lgs[v];
            float m = l[0];
            #pragma unroll
            for (int v = 1; v < NV; ++v) m = fmaxf(m, l[v]);
            float e[NV];
            #pragma unroll
            for (int v = 0; v < NV; ++v) e[v] = expf(l[v] - m);
            float s = ((e[0] + e[1]) + (e[2] + e[3])) + ((e[4] + e[5]) + (e[6] + e[7]));
            float w[NV];
            #pragma unroll
            for (int v = 0; v < NV; ++v) w[v] = e[v] / s;
            int am = 0; float wm = w[0];
            #pragma unroll
            for (int v = 1; v < NV; ++v) { if (w[v] > wm) { wm = w[v]; am = v; } }
            amax_out[row] = (float)am;
        }
        __syncthreads();
    }
}

extern "C" void kernel_launch(void* const* d_in, const int* in_sizes, int n_in,
                              void* d_out, int out_size, void* d_ws, size_t ws_size,
                              hipStream_t stream) {
    const float* query   = (const float*)d_in[0];
    const float* value   = (const float*)d_in[1];
    const float* grd_col = (const float*)d_in[2];
    const float* grd_row = (const float*)d_in[3];
    const float* Wv      = (const float*)d_in[4];
    const float* bv      = (const float*)d_in[5];
    const float* Wo      = (const float*)d_in[6];
    const float* bo      = (const float*)d_in[7];
    const float* Wa      = (const float*)d_in[8];
    const float* ba      = (const float*)d_in[9];
    const float* Wout    = (const float*)d_in[10];
    const float* bout    = (const float*)d_in[11];
    const float* Wp      = (const float*)d_in[12];
    const float* bp      = (const float*)d_in[13];

    float* out  = (float*)d_out;
    float* ws   = (float*)d_ws;
    float* offn = ws;                                        // 32768*64 f32
    float* attn = offn + (size_t)NROW * 64;                  // 32768*32 f32
    float* v2d  = attn + (size_t)NROW * 32;                  // 8464*256 f32
    float* wp2f = v2d + (size_t)BS * NPIX * C_;              // 256 f32
    float* S32  = wp2f + C_;                                 // 8464*8 f32
    int* cnt    = (int*)(S32 + (size_t)BS * NPIX * HEADS);   // 1 int (padded to 4 -> VW 16B-aligned)
    int* list   = cnt + 4;                                   // 32768 int
    ushort_t* VW = (ushort_t*)(list + NROW);                 // 8464*256 fp16
    float* WvWout = (float*)(VW + (size_t)BS * NPIX * C_);   // 256*256 f32
    float* bvW    = WvWout + C_ * C_;                        // 256 f32
    float* amax = out + (size_t)NROW * C_;

    prep_kernel<<<65, 256, 0, stream>>>(Wout, Wp, Wv, bv, WvWout, wp2f, bvW, cnt);
    proj_val_kernel<<<NVBLK2, 256, 0, stream>>>(value, Wv, bv, WvWout, bvW, wp2f,
                                                v2d, VW, S32);
    proj_qry_kernel<<<NQBLK, 256, 0, stream>>>(query, Wo, bo, Wa, ba, offn, attn);
    fused_kernel<<<NROW, 256, 0, stream>>>(VW, offn, attn, grd_col, grd_row, S32,
                                           query, bout, out, amax, cnt, list);
    exact_kernel<<<512, 256, 0, stream>>>(v2d, offn, attn, grd_col, grd_row,
                                          Wout, bout, Wp, bp, query, cnt, list, amax);
}

// Round 8
// 226.324 us; speedup vs baseline: 1.0665x; 1.0665x over previous
//
#include <hip/hip_runtime.h>
#include <hip/hip_fp16.h>

#define NV 8
#define NQ 4096
#define C_ 256
#define HEADS 8
#define PTS 4
#define HV 23
#define WV 46
#define NPIX (HV*WV)       // 1058
#define BS 8
#define NROW (BS*NQ)       // 32768
#define NVBLK2 ((BS*NPIX)/16) // 529 value blocks (16 rows each)
#define NQBLK (NROW/16)       // 2048 query blocks

typedef unsigned short ushort_t;
typedef unsigned int uint_t;

// ---------------- prep (65 blocks): 0..63 WvWout = Wv@Wout; 64: wp2f = Wout@Wp, bvW = bv@Wout, cnt=0 ----------------
__global__ void prep_kernel(const float* __restrict__ Wout, const float* __restrict__ Wp,
                            const float* __restrict__ Wv, const float* __restrict__ bv,
                            float* __restrict__ WvWout, float* __restrict__ wp2f,
                            float* __restrict__ bvW, int* __restrict__ cnt) {
    int blk = blockIdx.x;
    int t = threadIdx.x;
    __shared__ float rows[4][C_];
    if (blk < 64) {
        int r0 = blk * 4;
        #pragma unroll
        for (int r = 0; r < 4; ++r) rows[r][t] = Wv[(r0 + r) * C_ + t];
        __syncthreads();
        float acc[4] = {0.f, 0.f, 0.f, 0.f};
        for (int k = 0; k < C_; ++k) {
            float w = Wout[k * C_ + t];
            acc[0] = fmaf(rows[0][k], w, acc[0]);
            acc[1] = fmaf(rows[1][k], w, acc[1]);
            acc[2] = fmaf(rows[2][k], w, acc[2]);
            acc[3] = fmaf(rows[3][k], w, acc[3]);
        }
        #pragma unroll
        for (int r = 0; r < 4; ++r) WvWout[(r0 + r) * C_ + t] = acc[r];
    } else {
        if (t == 0) *cnt = 0;
        float a = 0.f;
        for (int c = 0; c < C_; ++c) a = fmaf(Wout[t * C_ + c], Wp[c], a);
        wp2f[t] = a;
        float fb = 0.f;
        for (int d = 0; d < C_; ++d) fb = fmaf(bv[d], Wout[d * C_ + t], fb);
        bvW[t] = fb;
    }
}

// ---------------- proj: value blocks (16 rows, one k-loop: v2d exact + VW) + reg S32; query blocks ----------------
// R2-verified structure (local optimum across R3/R4/R7 restructures: value LDS/VMEM/FMA pipes balanced,
// minimal weight traffic; query part 96/128 active lanes but lowest total time measured).
__global__ void proj_kernel(const float* __restrict__ value, const float* __restrict__ Wv,
                            const float* __restrict__ bv, const float* __restrict__ WvWout,
                            const float* __restrict__ bvW, const float* __restrict__ wp2f,
                            const float* __restrict__ query,
                            const float* __restrict__ Wo, const float* __restrict__ bo,
                            const float* __restrict__ Wa, const float* __restrict__ ba,
                            float* __restrict__ v2d, ushort_t* __restrict__ VW,
                            float* __restrict__ S32, float* __restrict__ offn,
                            float* __restrict__ attn) {
#pragma clang fp contract(off)
    __shared__ float sbuf[16 * C_ + 16 * 32];
    int blk = blockIdx.x;
    int t = threadIdx.x;
    if (blk < NVBLK2) {
        // ===== value part: 16 rows/block, single k-loop, 32 accumulator chains =====
        float (*rows)[C_] = (float (*)[C_])sbuf;             // [16][256] value rows
        int r0 = blk * 16;
        #pragma unroll
        for (int i = 0; i < 16; ++i) {
            int idx = t + i * 256;
            rows[idx >> 8][idx & 255] = value[(size_t)r0 * C_ + idx];
        }
        __syncthreads();
        float acc[16], accW[16];
        #pragma unroll
        for (int r = 0; r < 16; ++r) { acc[r] = 0.f; accW[r] = 0.f; }
        for (int k4 = 0; k4 < C_ / 4; ++k4) {
            int k = k4 * 4;
            float w0 = Wv[(k + 0) * C_ + t], w1 = Wv[(k + 1) * C_ + t];
            float w2 = Wv[(k + 2) * C_ + t], w3 = Wv[(k + 3) * C_ + t];
            float u0 = WvWout[(k + 0) * C_ + t], u1 = WvWout[(k + 1) * C_ + t];
            float u2 = WvWout[(k + 2) * C_ + t], u3 = WvWout[(k + 3) * C_ + t];
            #pragma unroll
            for (int r = 0; r < 16; ++r) {
                const float4 qv = *(reinterpret_cast<const float4*>(rows[r]) + k4);
                acc[r] = __builtin_fmaf(qv.x, w0, acc[r]);   // exact: sequential k order
                acc[r] = __builtin_fmaf(qv.y, w1, acc[r]);
                acc[r] = __builtin_fmaf(qv.z, w2, acc[r]);
                acc[r] = __builtin_fmaf(qv.w, w3, acc[r]);
                accW[r] = fmaf(qv.x, u0, accW[r]);
                accW[r] = fmaf(qv.y, u1, accW[r]);
                accW[r] = fmaf(qv.z, u2, accW[r]);
                accW[r] = fmaf(qv.w, u3, accW[r]);
            }
        }
        float b = bv[t];
        float b2 = bvW[t];
        #pragma unroll
        for (int r = 0; r < 16; ++r) {
            acc[r] = acc[r] + b;   // vd
            v2d[(size_t)(r0 + r) * C_ + t] = acc[r];
            VW[(size_t)(r0 + r) * C_ + t] = __half_as_ushort(__float2half(accW[r] + b2));
        }
        // S32[row][head] via 32-lane register reduce (head = t>>5)
        float wpt = wp2f[t];
        #pragma unroll
        for (int r = 0; r < 16; ++r) {
            float p = acc[r] * wpt;
            p += __shfl_down(p, 16, 32);
            p += __shfl_down(p, 8, 32);
            p += __shfl_down(p, 4, 32);
            p += __shfl_down(p, 2, 32);
            p += __shfl_down(p, 1, 32);
            if ((t & 31) == 0) S32[(size_t)(r0 + r) * HEADS + (t >> 5)] = p;
        }
    } else {
        // ===== query part: 16 rows/block, two independent 128-thread halves, float4 LDS =====
        int qb = blk - NVBLK2;
        int half = t >> 7, tt = t & 127;
        int rb = qb * 16 + half * 8;
        float (*qs)[C_] = (float (*)[C_])sbuf;
        float (*lg)[32] = (float (*)[32])(sbuf + 16 * C_);
        #pragma unroll
        for (int i = 0; i < 16; ++i) {
            int idx = tt + i * 128;
            int rr = idx >> 8, cc = idx & 255;
            qs[half * 8 + rr][cc] = query[(size_t)(rb + rr) * C_ + cc];
        }
        __syncthreads();
        if (tt < 64) {
            float acc[8] = {0.f, 0.f, 0.f, 0.f, 0.f, 0.f, 0.f, 0.f};
            for (int k4 = 0; k4 < C_ / 4; ++k4) {
                int k = k4 * 4;
                float w0 = Wo[(k + 0) * 64 + tt], w1 = Wo[(k + 1) * 64 + tt];
                float w2 = Wo[(k + 2) * 64 + tt], w3 = Wo[(k + 3) * 64 + tt];
                #pragma unroll
                for (int r = 0; r < 8; ++r) {
                    const float4 qv = *(reinterpret_cast<const float4*>(qs[half * 8 + r]) + k4);
                    acc[r] = __builtin_fmaf(qv.x, w0, acc[r]);
                    acc[r] = __builtin_fmaf(qv.y, w1, acc[r]);
                    acc[r] = __builtin_fmaf(qv.z, w2, acc[r]);
                    acc[r] = __builtin_fmaf(qv.w, w3, acc[r]);
                }
            }
            float b = bo[tt];
            float nrm = (tt & 1) ? 23.0f : 46.0f;
            #pragma unroll
            for (int r = 0; r < 8; ++r) offn[(size_t)(rb + r) * 64 + tt] = (acc[r] + b) / nrm;
        } else if (tt < 96) {
            int j = tt - 64;
            float acc[8] = {0.f, 0.f, 0.f, 0.f, 0.f, 0.f, 0.f, 0.f};
            for (int k4 = 0; k4 < C_ / 4; ++k4) {
                int k = k4 * 4;
                float w0 = Wa[(k + 0) * 32 + j], w1 = Wa[(k + 1) * 32 + j];
                float w2 = Wa[(k + 2) * 32 + j], w3 = Wa[(k + 3) * 32 + j];
                #pragma unroll
                for (int r = 0; r < 8; ++r) {
                    const float4 qv = *(reinterpret_cast<const float4*>(qs[half * 8 + r]) + k4);
                    acc[r] = __builtin_fmaf(qv.x, w0, acc[r]);
                    acc[r] = __builtin_fmaf(qv.y, w1, acc[r]);
                    acc[r] = __builtin_fmaf(qv.z, w2, acc[r]);
                    acc[r] = __builtin_fmaf(qv.w, w3, acc[r]);
                }
            }
            float b = ba[j];
            #pragma unroll
            for (int r = 0; r < 8; ++r) lg[half * 8 + r][j] = acc[r] + b;
        }
        __syncthreads();
        if (tt < 64) {
            int r = tt >> 3, h = tt & 7;
            int lr = half * 8 + r;
            float v0 = lg[lr][h * 4 + 0], v1 = lg[lr][h * 4 + 1];
            float v2 = lg[lr][h * 4 + 2], v3 = lg[lr][h * 4 + 3];
            float m = fmaxf(fmaxf(fmaxf(v0, v1), v2), v3);
            float e0 = expf(v0 - m), e1 = expf(v1 - m), e2 = expf(v2 - m), e3 = expf(v3 - m);
            float s = ((e0 + e1) + e2) + e3;
            attn[(size_t)(rb + r) * 32 + h * 4 + 0] = e0 / s;
            attn[(size_t)(rb + r) * 32 + h * 4 + 1] = e1 / s;
            attn[(size_t)(rb + r) * 32 + h * 4 + 2] = e2 / s;
            attn[(size_t)(rb + r) * 32 + h * 4 + 3] = e3 / s;
        }
    }
}

// ---------------- fused: f32 gap-tested logits (S32) + hfma2 sampling; R0 plain LDS layout ----------------
__global__ void __launch_bounds__(256) fused_kernel(
        const ushort_t* __restrict__ VW, const float* __restrict__ offn,
        const float* __restrict__ attn, const float* __restrict__ grd_col,
        const float* __restrict__ grd_row, const float* __restrict__ S32,
        const float* __restrict__ query, const float* __restrict__ bout,
        float* __restrict__ out, float* __restrict__ amax_out,
        int* __restrict__ cnt, int* __restrict__ list) {
    int bid = blockIdx.x;
    int row = ((bid & 7) << 12) | (bid >> 3);   // XCD-bijective: batch <-> XCD affinity
    int b = row >> 12;
    int q = row & (NQ - 1);
    int t = threadIdx.x;
    __shared__ __align__(16) int   g_ip[256][4];
    __shared__ __align__(16) float g_w[256][4];
    __shared__ __align__(16) float red[NV][C_];
    __shared__ float logits_sh[NV];
    __shared__ float wf_sh[NV];

    // ---- phase A (f32): t = v*32 + (h*4+p)
    {
        int v = t >> 5, r = t & 31, h = r >> 2;
        const float2 off2 = ((const float2*)(offn + (size_t)row * 64))[r];
        float at = attn[(size_t)row * 32 + r];
        float refx = grd_col[q * NV + v];
        float refy = grd_row[q * NV + v];
        float lx = refx + off2.x;
        float ly = refy + off2.y;
        float x = lx * 46.0f - 0.5f;
        float y = ly * 23.0f - 0.5f;
        float x0f = floorf(x), y0f = floorf(y);
        float wx1 = x - x0f, wy1 = y - y0f;
        float wx0 = 1.0f - wx1, wy0 = 1.0f - wy1;
        int xi = (int)x0f, yi = (int)y0f;
        bool vx0 = (x0f >= 0.0f) && (x0f < 46.0f);
        bool vx1 = (x0f + 1.0f >= 0.0f) && (x0f + 1.0f < 46.0f);
        bool vy0 = (y0f >= 0.0f) && (y0f < 23.0f);
        bool vy1 = (y0f + 1.0f >= 0.0f) && (y0f + 1.0f < 23.0f);
        int xc0 = min(max(xi, 0), WV - 1), xc1 = min(max(xi + 1, 0), WV - 1);
        int yc0 = min(max(yi, 0), HV - 1), yc1 = min(max(yi + 1, 0), HV - 1);
        float w00 = (vx0 && vy0) ? wx0 * wy0 : 0.0f;
        float w10 = (vx1 && vy0) ? wx1 * wy0 : 0.0f;
        float w01 = (vx0 && vy1) ? wx0 * wy1 : 0.0f;
        float w11 = (vx1 && vy1) ? wx1 * wy1 : 0.0f;
        int ip00 = yc0 * WV + xc0, ip10 = yc0 * WV + xc1;
        int ip01 = yc1 * WV + xc0, ip11 = yc1 * WV + xc1;

        g_ip[t][0] = ip00 * (C_ * 2); g_ip[t][1] = ip10 * (C_ * 2);   // byte offsets
        g_ip[t][2] = ip01 * (C_ * 2); g_ip[t][3] = ip11 * (C_ * 2);
        g_w[t][0] = w00 * at;  g_w[t][1] = w10 * at;
        g_w[t][2] = w01 * at;  g_w[t][3] = w11 * at;

        const float* Sb = S32 + (size_t)b * NPIX * HEADS;
        float samp = w00 * Sb[ip00 * HEADS + h] + w10 * Sb[ip10 * HEADS + h]
                   + w01 * Sb[ip01 * HEADS + h] + w11 * Sb[ip11 * HEADS + h];
        float contrib = at * samp;
        #pragma unroll
        for (int s2 = 16; s2; s2 >>= 1) contrib += __shfl_down(contrib, s2, 32);
        if (r == 0) logits_sh[v] = contrib;
    }
    __syncthreads();                                   // barrier 1 (A -> B)

    // ---- lanes 0..7 (f32): argmax + gap test + softmax weights
    if (t < 8) {
        float m = logits_sh[0]; int am = 0;
        #pragma unroll
        for (int v2 = 1; v2 < NV; ++v2) {
            float lv = logits_sh[v2];
            if (lv > m) { m = lv; am = v2; }
        }
        float e = expf(logits_sh[t] - m);
        float ssum = e;
        ssum += __shfl_xor(ssum, 1, 8);
        ssum += __shfl_xor(ssum, 2, 8);
        ssum += __shfl_xor(ssum, 4, 8);
        wf_sh[t] = e / ssum;
        if (t == 0) {
            amax_out[row] = (float)am;
            float m2 = -1e30f;
            #pragma unroll
            for (int v2 = 0; v2 < NV; ++v2) {
                float lv = logits_sh[v2];
                if (v2 != am && lv > m2) m2 = lv;
            }
            float thr = 1e-4f * fmaxf(1.0f, fabsf(m));
            if ((m - m2) < thr) {
                int idx = atomicAdd(cnt, 1);
                list[idx] = row;
            }
        }
    }

    // ---- phase B: 8 groups x 32 threads; group g = v; 8 channels/thread; packed f16 FMA
    {
        int g = t >> 5, lt = t & 31;
        int c0 = lt * 8;
        int c2 = c0 * 2;               // channel byte offset
        int hb = lt >> 2;
        const char* vb = (const char*)(VW + (size_t)b * NPIX * C_);
        __half2 h01 = __float2half2_rn(0.f);
        __half2 h23 = h01, h45 = h01, h67 = h01;
        #pragma unroll
        for (int pp = 0; pp < 2; ++pp) {
            int e0 = g * 32 + hb * 4 + pp * 2;         // entry (v=g, h=hb, p=pp*2); +1 -> p+1
            const int4   ipA = *reinterpret_cast<const int4*>(g_ip[e0]);
            const float4 wA  = *reinterpret_cast<const float4*>(g_w[e0]);
            const int4   ipB = *reinterpret_cast<const int4*>(g_ip[e0 + 1]);
            const float4 wB  = *reinterpret_cast<const float4*>(g_w[e0 + 1]);
            const uint4 uA0 = *reinterpret_cast<const uint4*>(vb + (ipA.x + c2));
            const uint4 uA1 = *reinterpret_cast<const uint4*>(vb + (ipA.y + c2));
            const uint4 uA2 = *reinterpret_cast<const uint4*>(vb + (ipA.z + c2));
            const uint4 uA3 = *reinterpret_cast<const uint4*>(vb + (ipA.w + c2));
            const uint4 uB0 = *reinterpret_cast<const uint4*>(vb + (ipB.x + c2));
            const uint4 uB1 = *reinterpret_cast<const uint4*>(vb + (ipB.y + c2));
            const uint4 uB2 = *reinterpret_cast<const uint4*>(vb + (ipB.z + c2));
            const uint4 uB3 = *reinterpret_cast<const uint4*>(vb + (ipB.w + c2));
            #define CORNER(W, U) { \
                const __half2 wh = __float2half2_rn(W); \
                h01 = __hfma2(wh, *reinterpret_cast<const __half2*>(&U.x), h01); \
                h23 = __hfma2(wh, *reinterpret_cast<const __half2*>(&U.y), h23); \
                h45 = __hfma2(wh, *reinterpret_cast<const __half2*>(&U.z), h45); \
                h67 = __hfma2(wh, *reinterpret_cast<const __half2*>(&U.w), h67); }
            CORNER(wA.x, uA0)
            CORNER(wA.y, uA1)
            CORNER(wA.z, uA2)
            CORNER(wA.w, uA3)
            CORNER(wB.x, uB0)
            CORNER(wB.y, uB1)
            CORNER(wB.z, uB2)
            CORNER(wB.w, uB3)
            #undef CORNER
        }
        float a0 = __low2float(h01), a1 = __high2float(h01);
        float a2 = __low2float(h23), a3 = __high2float(h23);
        float a4 = __low2float(h45), a5 = __high2float(h45);
        float a6 = __low2float(h67), a7 = __high2float(h67);
        float4 s0v = {a0, a1, a2, a3}, s1v = {a4, a5, a6, a7};
        *reinterpret_cast<float4*>(&red[g][c0])     = s0v;
        *reinterpret_cast<float4*>(&red[g][c0 + 4]) = s1v;
    }
    __syncthreads();                                   // barrier 2 (B -> epilogue)
    float O = 0.f;
    #pragma unroll
    for (int g8 = 0; g8 < NV; ++g8) O = fmaf(wf_sh[g8], red[g8][t], O);
    out[(size_t)row * C_ + t] = O + bout[t] + 2.0f * query[(size_t)row * C_ + t];
}

// ---------------- exact replication (compacted: grid-stride over flagged list) ----------------
__global__ void __launch_bounds__(256) exact_kernel(
        const float* __restrict__ v2d, const float* __restrict__ offn,
        const float* __restrict__ attn, const float* __restrict__ grd_col,
        const float* __restrict__ grd_row, const float* __restrict__ Wout,
        const float* __restrict__ bout, const float* __restrict__ Wp,
        const float* __restrict__ bp, const float* __restrict__ query,
        const int* __restrict__ cnt, const int* __restrict__ list,
        float* __restrict__ amax_out) {
#pragma clang fp contract(off)
    int n = *cnt;
    int t = threadIdx.x;
    int h = t >> 5;
    __shared__ float s_off[64];
    __shared__ float s_attn[32];
    __shared__ float wp_lds[C_];
    __shared__ float out_l[NV][C_ + 1];
    __shared__ float bevs_l[NV][C_ + 1];
    __shared__ float lgs[NV];
    wp_lds[t] = Wp[t];

    for (int i = blockIdx.x; i < n; i += gridDim.x) {
        int row = list[i];
        int b = row >> 12;
        int q = row & (NQ - 1);
        if (t < 64)      s_off[t]       = offn[(size_t)row * 64 + t];
        else if (t < 96) s_attn[t - 64] = attn[(size_t)row * 32 + (t - 64)];
        __syncthreads();

        const float* vb = v2d + (size_t)b * NPIX * C_;
        #pragma unroll
        for (int v = 0; v < NV; ++v) {
            float refx = grd_col[q * NV + v];
            float refy = grd_row[q * NV + v];
            float acc = 0.0f;
            #pragma unroll
            for (int p = 0; p < PTS; ++p) {
                float lx = refx + s_off[h * 8 + p * 2 + 0];
                float ly = refy + s_off[h * 8 + p * 2 + 1];
                float x = lx * 46.0f - 0.5f;
                float y = ly * 23.0f - 0.5f;
                float x0f = floorf(x), y0f = floorf(y);
                float wx1 = x - x0f, wy1 = y - y0f;
                float wx0 = 1.0f - wx1, wy0 = 1.0f - wy1;
                int xi = (int)x0f, yi = (int)y0f;
                bool vx0 = (x0f >= 0.0f) && (x0f < 46.0f);
                bool vx1 = (x0f + 1.0f >= 0.0f) && (x0f + 1.0f < 46.0f);
                bool vy0 = (y0f >= 0.0f) && (y0f < 23.0f);
                bool vy1 = (y0f + 1.0f >= 0.0f) && (y0f + 1.0f < 23.0f);
                int xc0 = min(max(xi, 0), WV - 1), xc1 = min(max(xi + 1, 0), WV - 1);
                int yc0 = min(max(yi, 0), HV - 1), yc1 = min(max(yi + 1, 0), HV - 1);
                float g00 = (vx0 && vy0) ? vb[(yc0 * WV + xc0) * C_ + t] : 0.0f;
                float g10 = (vx1 && vy0) ? vb[(yc0 * WV + xc1) * C_ + t] : 0.0f;
                float g01 = (vx0 && vy1) ? vb[(yc1 * WV + xc0) * C_ + t] : 0.0f;
                float g11 = (vx1 && vy1) ? vb[(yc1 * WV + xc1) * C_ + t] : 0.0f;
                float t00 = g00 * (wx0 * wy0);
                float t10 = g10 * (wx1 * wy0);
                float t01 = g01 * (wx0 * wy1);
                float t11 = g11 * (wx1 * wy1);
                float samp = ((t00 + t10) + t01) + t11;
                float pr = s_attn[h * 4 + p] * samp;
                acc = acc + pr;
            }
            out_l[v][t] = acc;
        }
        __syncthreads();

        float bacc[NV];
        #pragma unroll
        for (int v = 0; v < NV; ++v) bacc[v] = 0.f;
        for (int i2 = 0; i2 < C_; ++i2) {
            float w_it = Wout[i2 * C_ + t];
            #pragma unroll
            for (int v = 0; v < NV; ++v) bacc[v] = __builtin_fmaf(out_l[v][i2], w_it, bacc[v]);
        }
        float bo_t = bout[t];
        float qv = query[(size_t)row * C_ + t];
        #pragma unroll
        for (int v = 0; v < NV; ++v) bevs_l[v][t] = (bacc[v] + bo_t) + qv;
        __syncthreads();

        if (t < NV) {
            float lv = 0.f;
            for (int c = 0; c < C_; ++c) lv = __builtin_fmaf(bevs_l[t][c], wp_lds[c], lv);
            lgs[t] = lv + bp[0];
        }
        __syncthreads();

        if (t == 0) {
            float l[NV];
            #pragma unroll
            for (int v = 0; v < NV; ++v) l[v] = lgs[v];
            float m = l[0];
            #pragma unroll
            for (int v = 1; v < NV; ++v) m = fmaxf(m, l[v]);
            float e[NV];
            #pragma unroll
            for (int v = 0; v < NV; ++v) e[v] = expf(l[v] - m);
            float s = ((e[0] + e[1]) + (e[2] + e[3])) + ((e[4] + e[5]) + (e[6] + e[7]));
            float w[NV];
            #pragma unroll
            for (int v = 0; v < NV; ++v) w[v] = e[v] / s;
            int am = 0; float wm = w[0];
            #pragma unroll
            for (int v = 1; v < NV; ++v) { if (w[v] > wm) { wm = w[v]; am = v; } }
            amax_out[row] = (float)am;
        }
        __syncthreads();
    }
}

extern "C" void kernel_launch(void* const* d_in, const int* in_sizes, int n_in,
                              void* d_out, int out_size, void* d_ws, size_t ws_size,
                              hipStream_t stream) {
    const float* query   = (const float*)d_in[0];
    const float* value   = (const float*)d_in[1];
    const float* grd_col = (const float*)d_in[2];
    const float* grd_row = (const float*)d_in[3];
    const float* Wv      = (const float*)d_in[4];
    const float* bv      = (const float*)d_in[5];
    const float* Wo      = (const float*)d_in[6];
    const float* bo      = (const float*)d_in[7];
    const float* Wa      = (const float*)d_in[8];
    const float* ba      = (const float*)d_in[9];
    const float* Wout    = (const float*)d_in[10];
    const float* bout    = (const float*)d_in[11];
    const float* Wp      = (const float*)d_in[12];
    const float* bp      = (const float*)d_in[13];

    float* out  = (float*)d_out;
    float* ws   = (float*)d_ws;
    float* offn = ws;                                        // 32768*64 f32
    float* attn = offn + (size_t)NROW * 64;                  // 32768*32 f32
    float* v2d  = attn + (size_t)NROW * 32;                  // 8464*256 f32
    float* wp2f = v2d + (size_t)BS * NPIX * C_;              // 256 f32
    float* S32  = wp2f + C_;                                 // 8464*8 f32
    int* cnt    = (int*)(S32 + (size_t)BS * NPIX * HEADS);   // 1 int (padded to 4 -> VW 16B-aligned)
    int* list   = cnt + 4;                                   // 32768 int
    ushort_t* VW = (ushort_t*)(list + NROW);                 // 8464*256 fp16
    float* WvWout = (float*)(VW + (size_t)BS * NPIX * C_);   // 256*256 f32
    float* bvW    = WvWout + C_ * C_;                        // 256 f32
    float* amax = out + (size_t)NROW * C_;

    prep_kernel<<<65, 256, 0, stream>>>(Wout, Wp, Wv, bv, WvWout, wp2f, bvW, cnt);
    proj_kernel<<<NVBLK2 + NQBLK, 256, 0, stream>>>(value, Wv, bv, WvWout, bvW, wp2f,
                                                    query, Wo, bo, Wa, ba,
                                                    v2d, VW, S32, offn, attn);
    fused_kernel<<<NROW, 256, 0, stream>>>(VW, offn, attn, grd_col, grd_row, S32,
                                           query, bout, out, amax, cnt, list);
    exact_kernel<<<512, 256, 0, stream>>>(v2d, offn, attn, grd_col, grd_row,
                                          Wout, bout, Wp, bp, query, cnt, list, amax);
}

// Round 9
// 224.276 us; speedup vs baseline: 1.0763x; 1.0091x over previous
//
#include <hip/hip_runtime.h>
#include <hip/hip_fp16.h>

#define NV 8
#define NQ 4096
#define C_ 256
#define HEADS 8
#define PTS 4
#define HV 23
#define WV 46
#define NPIX (HV*WV)       // 1058
#define BS 8
#define NROW (BS*NQ)       // 32768
#define NVBLK2 ((BS*NPIX)/16) // 529 value blocks (16 rows each)
#define NQBLK (NROW/16)       // 2048 query blocks

typedef unsigned short ushort_t;
typedef unsigned int uint_t;

// ---------------- prep (65 blocks): 0..63 WvWout = Wv@Wout; 64: wp2f = Wout@Wp, bvW = bv@Wout, cnt=0 ----------------
__global__ void prep_kernel(const float* __restrict__ Wout, const float* __restrict__ Wp,
                            const float* __restrict__ Wv, const float* __restrict__ bv,
                            float* __restrict__ WvWout, float* __restrict__ wp2f,
                            float* __restrict__ bvW, int* __restrict__ cnt) {
    int blk = blockIdx.x;
    int t = threadIdx.x;
    __shared__ float rows[4][C_];
    if (blk < 64) {
        int r0 = blk * 4;
        #pragma unroll
        for (int r = 0; r < 4; ++r) rows[r][t] = Wv[(r0 + r) * C_ + t];
        __syncthreads();
        float acc[4] = {0.f, 0.f, 0.f, 0.f};
        for (int k = 0; k < C_; ++k) {
            float w = Wout[k * C_ + t];
            acc[0] = fmaf(rows[0][k], w, acc[0]);
            acc[1] = fmaf(rows[1][k], w, acc[1]);
            acc[2] = fmaf(rows[2][k], w, acc[2]);
            acc[3] = fmaf(rows[3][k], w, acc[3]);
        }
        #pragma unroll
        for (int r = 0; r < 4; ++r) WvWout[(r0 + r) * C_ + t] = acc[r];
    } else {
        if (t == 0) *cnt = 0;
        float a = 0.f;
        for (int c = 0; c < C_; ++c) a = fmaf(Wout[t * C_ + c], Wp[c], a);
        wp2f[t] = a;
        float fb = 0.f;
        for (int d = 0; d < C_; ++d) fb = fmaf(bv[d], Wout[d * C_ + t], fb);
        bvW[t] = fb;
    }
}

// ---------------- proj: value blocks (16 rows, one k-loop: v2d exact + VW) + reg S32; query blocks ----------------
// R2-verified structure (local optimum across R3/R4/R7 restructures).
__global__ void proj_kernel(const float* __restrict__ value, const float* __restrict__ Wv,
                            const float* __restrict__ bv, const float* __restrict__ WvWout,
                            const float* __restrict__ bvW, const float* __restrict__ wp2f,
                            const float* __restrict__ query,
                            const float* __restrict__ Wo, const float* __restrict__ bo,
                            const float* __restrict__ Wa, const float* __restrict__ ba,
                            float* __restrict__ v2d, ushort_t* __restrict__ VW,
                            float* __restrict__ S32, float* __restrict__ offn,
                            float* __restrict__ attn) {
#pragma clang fp contract(off)
    __shared__ float sbuf[16 * C_ + 16 * 32];
    int blk = blockIdx.x;
    int t = threadIdx.x;
    if (blk < NVBLK2) {
        // ===== value part: 16 rows/block, single k-loop, 32 accumulator chains =====
        float (*rows)[C_] = (float (*)[C_])sbuf;             // [16][256] value rows
        int r0 = blk * 16;
        #pragma unroll
        for (int i = 0; i < 16; ++i) {
            int idx = t + i * 256;
            rows[idx >> 8][idx & 255] = value[(size_t)r0 * C_ + idx];
        }
        __syncthreads();
        float acc[16], accW[16];
        #pragma unroll
        for (int r = 0; r < 16; ++r) { acc[r] = 0.f; accW[r] = 0.f; }
        for (int k4 = 0; k4 < C_ / 4; ++k4) {
            int k = k4 * 4;
            float w0 = Wv[(k + 0) * C_ + t], w1 = Wv[(k + 1) * C_ + t];
            float w2 = Wv[(k + 2) * C_ + t], w3 = Wv[(k + 3) * C_ + t];
            float u0 = WvWout[(k + 0) * C_ + t], u1 = WvWout[(k + 1) * C_ + t];
            float u2 = WvWout[(k + 2) * C_ + t], u3 = WvWout[(k + 3) * C_ + t];
            #pragma unroll
            for (int r = 0; r < 16; ++r) {
                const float4 qv = *(reinterpret_cast<const float4*>(rows[r]) + k4);
                acc[r] = __builtin_fmaf(qv.x, w0, acc[r]);   // exact: sequential k order
                acc[r] = __builtin_fmaf(qv.y, w1, acc[r]);
                acc[r] = __builtin_fmaf(qv.z, w2, acc[r]);
                acc[r] = __builtin_fmaf(qv.w, w3, acc[r]);
                accW[r] = fmaf(qv.x, u0, accW[r]);
                accW[r] = fmaf(qv.y, u1, accW[r]);
                accW[r] = fmaf(qv.z, u2, accW[r]);
                accW[r] = fmaf(qv.w, u3, accW[r]);
            }
        }
        float b = bv[t];
        float b2 = bvW[t];
        #pragma unroll
        for (int r = 0; r < 16; ++r) {
            acc[r] = acc[r] + b;   // vd
            v2d[(size_t)(r0 + r) * C_ + t] = acc[r];
            VW[(size_t)(r0 + r) * C_ + t] = __half_as_ushort(__float2half(accW[r] + b2));
        }
        // S32[row][head] via 32-lane register reduce (head = t>>5)
        float wpt = wp2f[t];
        #pragma unroll
        for (int r = 0; r < 16; ++r) {
            float p = acc[r] * wpt;
            p += __shfl_down(p, 16, 32);
            p += __shfl_down(p, 8, 32);
            p += __shfl_down(p, 4, 32);
            p += __shfl_down(p, 2, 32);
            p += __shfl_down(p, 1, 32);
            if ((t & 31) == 0) S32[(size_t)(r0 + r) * HEADS + (t >> 5)] = p;
        }
    } else {
        // ===== query part: 16 rows/block, two independent 128-thread halves, float4 LDS =====
        int qb = blk - NVBLK2;
        int half = t >> 7, tt = t & 127;
        int rb = qb * 16 + half * 8;
        float (*qs)[C_] = (float (*)[C_])sbuf;
        float (*lg)[32] = (float (*)[32])(sbuf + 16 * C_);
        #pragma unroll
        for (int i = 0; i < 16; ++i) {
            int idx = tt + i * 128;
            int rr = idx >> 8, cc = idx & 255;
            qs[half * 8 + rr][cc] = query[(size_t)(rb + rr) * C_ + cc];
        }
        __syncthreads();
        if (tt < 64) {
            float acc[8] = {0.f, 0.f, 0.f, 0.f, 0.f, 0.f, 0.f, 0.f};
            for (int k4 = 0; k4 < C_ / 4; ++k4) {
                int k = k4 * 4;
                float w0 = Wo[(k + 0) * 64 + tt], w1 = Wo[(k + 1) * 64 + tt];
                float w2 = Wo[(k + 2) * 64 + tt], w3 = Wo[(k + 3) * 64 + tt];
                #pragma unroll
                for (int r = 0; r < 8; ++r) {
                    const float4 qv = *(reinterpret_cast<const float4*>(qs[half * 8 + r]) + k4);
                    acc[r] = __builtin_fmaf(qv.x, w0, acc[r]);
                    acc[r] = __builtin_fmaf(qv.y, w1, acc[r]);
                    acc[r] = __builtin_fmaf(qv.z, w2, acc[r]);
                    acc[r] = __builtin_fmaf(qv.w, w3, acc[r]);
                }
            }
            float b = bo[tt];
            float nrm = (tt & 1) ? 23.0f : 46.0f;
            #pragma unroll
            for (int r = 0; r < 8; ++r) offn[(size_t)(rb + r) * 64 + tt] = (acc[r] + b) / nrm;
        } else if (tt < 96) {
            int j = tt - 64;
            float acc[8] = {0.f, 0.f, 0.f, 0.f, 0.f, 0.f, 0.f, 0.f};
            for (int k4 = 0; k4 < C_ / 4; ++k4) {
                int k = k4 * 4;
                float w0 = Wa[(k + 0) * 32 + j], w1 = Wa[(k + 1) * 32 + j];
                float w2 = Wa[(k + 2) * 32 + j], w3 = Wa[(k + 3) * 32 + j];
                #pragma unroll
                for (int r = 0; r < 8; ++r) {
                    const float4 qv = *(reinterpret_cast<const float4*>(qs[half * 8 + r]) + k4);
                    acc[r] = __builtin_fmaf(qv.x, w0, acc[r]);
                    acc[r] = __builtin_fmaf(qv.y, w1, acc[r]);
                    acc[r] = __builtin_fmaf(qv.z, w2, acc[r]);
                    acc[r] = __builtin_fmaf(qv.w, w3, acc[r]);
                }
            }
            float b = ba[j];
            #pragma unroll
            for (int r = 0; r < 8; ++r) lg[half * 8 + r][j] = acc[r] + b;
        }
        __syncthreads();
        if (tt < 64) {
            int r = tt >> 3, h = tt & 7;
            int lr = half * 8 + r;
            float v0 = lg[lr][h * 4 + 0], v1 = lg[lr][h * 4 + 1];
            float v2 = lg[lr][h * 4 + 2], v3 = lg[lr][h * 4 + 3];
            float m = fmaxf(fmaxf(fmaxf(v0, v1), v2), v3);
            float e0 = expf(v0 - m), e1 = expf(v1 - m), e2 = expf(v2 - m), e3 = expf(v3 - m);
            float s = ((e0 + e1) + e2) + e3;
            attn[(size_t)(rb + r) * 32 + h * 4 + 0] = e0 / s;
            attn[(size_t)(rb + r) * 32 + h * 4 + 1] = e1 / s;
            attn[(size_t)(rb + r) * 32 + h * 4 + 2] = e2 / s;
            attn[(size_t)(rb + r) * 32 + h * 4 + 3] = e3 / s;
        }
    }
}

// ---------------- fused: f32 gap-tested logits (S32) + hfma2 sampling ----------------
// vs R8: corner weights converted to duplicated half2 ONCE in phase A (was 16 redundant
// f32->half2 cvts per B thread). Same f32 value, same rn conversion -> bit-identical output.
__global__ void __launch_bounds__(256) fused_kernel(
        const ushort_t* __restrict__ VW, const float* __restrict__ offn,
        const float* __restrict__ attn, const float* __restrict__ grd_col,
        const float* __restrict__ grd_row, const float* __restrict__ S32,
        const float* __restrict__ query, const float* __restrict__ bout,
        float* __restrict__ out, float* __restrict__ amax_out,
        int* __restrict__ cnt, int* __restrict__ list) {
    int bid = blockIdx.x;
    int row = ((bid & 7) << 12) | (bid >> 3);   // XCD-bijective: batch <-> XCD affinity
    int b = row >> 12;
    int q = row & (NQ - 1);
    int t = threadIdx.x;
    __shared__ __align__(16) int     g_ip[256][4];
    __shared__ __align__(16) __half2 g_wh[256][4];   // duplicated half2 per corner weight
    __shared__ __align__(16) float red[NV][C_];
    __shared__ float logits_sh[NV];
    __shared__ float wf_sh[NV];

    // ---- phase A (f32): t = v*32 + (h*4+p)
    {
        int v = t >> 5, r = t & 31, h = r >> 2;
        const float2 off2 = ((const float2*)(offn + (size_t)row * 64))[r];
        float at = attn[(size_t)row * 32 + r];
        float refx = grd_col[q * NV + v];
        float refy = grd_row[q * NV + v];
        float lx = refx + off2.x;
        float ly = refy + off2.y;
        float x = lx * 46.0f - 0.5f;
        float y = ly * 23.0f - 0.5f;
        float x0f = floorf(x), y0f = floorf(y);
        float wx1 = x - x0f, wy1 = y - y0f;
        float wx0 = 1.0f - wx1, wy0 = 1.0f - wy1;
        int xi = (int)x0f, yi = (int)y0f;
        bool vx0 = (x0f >= 0.0f) && (x0f < 46.0f);
        bool vx1 = (x0f + 1.0f >= 0.0f) && (x0f + 1.0f < 46.0f);
        bool vy0 = (y0f >= 0.0f) && (y0f < 23.0f);
        bool vy1 = (y0f + 1.0f >= 0.0f) && (y0f + 1.0f < 23.0f);
        int xc0 = min(max(xi, 0), WV - 1), xc1 = min(max(xi + 1, 0), WV - 1);
        int yc0 = min(max(yi, 0), HV - 1), yc1 = min(max(yi + 1, 0), HV - 1);
        float w00 = (vx0 && vy0) ? wx0 * wy0 : 0.0f;
        float w10 = (vx1 && vy0) ? wx1 * wy0 : 0.0f;
        float w01 = (vx0 && vy1) ? wx0 * wy1 : 0.0f;
        float w11 = (vx1 && vy1) ? wx1 * wy1 : 0.0f;
        int ip00 = yc0 * WV + xc0, ip10 = yc0 * WV + xc1;
        int ip01 = yc1 * WV + xc0, ip11 = yc1 * WV + xc1;

        g_ip[t][0] = ip00 * (C_ * 2); g_ip[t][1] = ip10 * (C_ * 2);   // byte offsets
        g_ip[t][2] = ip01 * (C_ * 2); g_ip[t][3] = ip11 * (C_ * 2);
        __half hw0 = __float2half(w00 * at);
        __half hw1 = __float2half(w10 * at);
        __half hw2 = __float2half(w01 * at);
        __half hw3 = __float2half(w11 * at);
        g_wh[t][0] = __halves2half2(hw0, hw0);
        g_wh[t][1] = __halves2half2(hw1, hw1);
        g_wh[t][2] = __halves2half2(hw2, hw2);
        g_wh[t][3] = __halves2half2(hw3, hw3);

        const float* Sb = S32 + (size_t)b * NPIX * HEADS;
        float samp = w00 * Sb[ip00 * HEADS + h] + w10 * Sb[ip10 * HEADS + h]
                   + w01 * Sb[ip01 * HEADS + h] + w11 * Sb[ip11 * HEADS + h];
        float contrib = at * samp;
        #pragma unroll
        for (int s2 = 16; s2; s2 >>= 1) contrib += __shfl_down(contrib, s2, 32);
        if (r == 0) logits_sh[v] = contrib;
    }
    __syncthreads();                                   // barrier 1 (A -> B)

    // ---- lanes 0..7 (f32): argmax + gap test + softmax weights
    if (t < 8) {
        float m = logits_sh[0]; int am = 0;
        #pragma unroll
        for (int v2 = 1; v2 < NV; ++v2) {
            float lv = logits_sh[v2];
            if (lv > m) { m = lv; am = v2; }
        }
        float e = expf(logits_sh[t] - m);
        float ssum = e;
        ssum += __shfl_xor(ssum, 1, 8);
        ssum += __shfl_xor(ssum, 2, 8);
        ssum += __shfl_xor(ssum, 4, 8);
        wf_sh[t] = e / ssum;
        if (t == 0) {
            amax_out[row] = (float)am;
            float m2 = -1e30f;
            #pragma unroll
            for (int v2 = 0; v2 < NV; ++v2) {
                float lv = logits_sh[v2];
                if (v2 != am && lv > m2) m2 = lv;
            }
            float thr = 1e-4f * fmaxf(1.0f, fabsf(m));
            if ((m - m2) < thr) {
                int idx = atomicAdd(cnt, 1);
                list[idx] = row;
            }
        }
    }

    // ---- phase B: 8 groups x 32 threads; group g = v; 8 channels/thread; packed f16 FMA
    {
        int g = t >> 5, lt = t & 31;
        int c0 = lt * 8;
        int c2 = c0 * 2;               // channel byte offset
        int hb = lt >> 2;
        const char* vb = (const char*)(VW + (size_t)b * NPIX * C_);
        __half2 h01 = __float2half2_rn(0.f);
        __half2 h23 = h01, h45 = h01, h67 = h01;
        #pragma unroll
        for (int pp = 0; pp < 2; ++pp) {
            int e0 = g * 32 + hb * 4 + pp * 2;         // entry (v=g, h=hb, p=pp*2); +1 -> p+1
            const int4   ipA = *reinterpret_cast<const int4*>(g_ip[e0]);
            const uint4  whA = *reinterpret_cast<const uint4*>(g_wh[e0]);
            const int4   ipB = *reinterpret_cast<const int4*>(g_ip[e0 + 1]);
            const uint4  whB = *reinterpret_cast<const uint4*>(g_wh[e0 + 1]);
            const uint4 uA0 = *reinterpret_cast<const uint4*>(vb + (ipA.x + c2));
            const uint4 uA1 = *reinterpret_cast<const uint4*>(vb + (ipA.y + c2));
            const uint4 uA2 = *reinterpret_cast<const uint4*>(vb + (ipA.z + c2));
            const uint4 uA3 = *reinterpret_cast<const uint4*>(vb + (ipA.w + c2));
            const uint4 uB0 = *reinterpret_cast<const uint4*>(vb + (ipB.x + c2));
            const uint4 uB1 = *reinterpret_cast<const uint4*>(vb + (ipB.y + c2));
            const uint4 uB2 = *reinterpret_cast<const uint4*>(vb + (ipB.z + c2));
            const uint4 uB3 = *reinterpret_cast<const uint4*>(vb + (ipB.w + c2));
            #define CORNER(WHU, U) { \
                const __half2 wh = *reinterpret_cast<const __half2*>(&WHU); \
                h01 = __hfma2(wh, *reinterpret_cast<const __half2*>(&U.x), h01); \
                h23 = __hfma2(wh, *reinterpret_cast<const __half2*>(&U.y), h23); \
                h45 = __hfma2(wh, *reinterpret_cast<const __half2*>(&U.z), h45); \
                h67 = __hfma2(wh, *reinterpret_cast<const __half2*>(&U.w), h67); }
            CORNER(whA.x, uA0)
            CORNER(whA.y, uA1)
            CORNER(whA.z, uA2)
            CORNER(whA.w, uA3)
            CORNER(whB.x, uB0)
            CORNER(whB.y, uB1)
            CORNER(whB.z, uB2)
            CORNER(whB.w, uB3)
            #undef CORNER
        }
        float a0 = __low2float(h01), a1 = __high2float(h01);
        float a2 = __low2float(h23), a3 = __high2float(h23);
        float a4 = __low2float(h45), a5 = __high2float(h45);
        float a6 = __low2float(h67), a7 = __high2float(h67);
        float4 s0v = {a0, a1, a2, a3}, s1v = {a4, a5, a6, a7};
        *reinterpret_cast<float4*>(&red[g][c0])     = s0v;
        *reinterpret_cast<float4*>(&red[g][c0 + 4]) = s1v;
    }
    __syncthreads();                                   // barrier 2 (B -> epilogue)
    float O = 0.f;
    #pragma unroll
    for (int g8 = 0; g8 < NV; ++g8) O = fmaf(wf_sh[g8], red[g8][t], O);
    out[(size_t)row * C_ + t] = O + bout[t] + 2.0f * query[(size_t)row * C_ + t];
}

// ---------------- exact replication (compacted: grid-stride over flagged list) ----------------
__global__ void __launch_bounds__(256) exact_kernel(
        const float* __restrict__ v2d, const float* __restrict__ offn,
        const float* __restrict__ attn, const float* __restrict__ grd_col,
        const float* __restrict__ grd_row, const float* __restrict__ Wout,
        const float* __restrict__ bout, const float* __restrict__ Wp,
        const float* __restrict__ bp, const float* __restrict__ query,
        const int* __restrict__ cnt, const int* __restrict__ list,
        float* __restrict__ amax_out) {
#pragma clang fp contract(off)
    int n = *cnt;
    int t = threadIdx.x;
    int h = t >> 5;
    __shared__ float s_off[64];
    __shared__ float s_attn[32];
    __shared__ float wp_lds[C_];
    __shared__ float out_l[NV][C_ + 1];
    __shared__ float bevs_l[NV][C_ + 1];
    __shared__ float lgs[NV];
    wp_lds[t] = Wp[t];

    for (int i = blockIdx.x; i < n; i += gridDim.x) {
        int row = list[i];
        int b = row >> 12;
        int q = row & (NQ - 1);
        if (t < 64)      s_off[t]       = offn[(size_t)row * 64 + t];
        else if (t < 96) s_attn[t - 64] = attn[(size_t)row * 32 + (t - 64)];
        __syncthreads();

        const float* vb = v2d + (size_t)b * NPIX * C_;
        #pragma unroll
        for (int v = 0; v < NV; ++v) {
            float refx = grd_col[q * NV + v];
            float refy = grd_row[q * NV + v];
            float acc = 0.0f;
            #pragma unroll
            for (int p = 0; p < PTS; ++p) {
                float lx = refx + s_off[h * 8 + p * 2 + 0];
                float ly = refy + s_off[h * 8 + p * 2 + 1];
                float x = lx * 46.0f - 0.5f;
                float y = ly * 23.0f - 0.5f;
                float x0f = floorf(x), y0f = floorf(y);
                float wx1 = x - x0f, wy1 = y - y0f;
                float wx0 = 1.0f - wx1, wy0 = 1.0f - wy1;
                int xi = (int)x0f, yi = (int)y0f;
                bool vx0 = (x0f >= 0.0f) && (x0f < 46.0f);
                bool vx1 = (x0f + 1.0f >= 0.0f) && (x0f + 1.0f < 46.0f);
                bool vy0 = (y0f >= 0.0f) && (y0f < 23.0f);
                bool vy1 = (y0f + 1.0f >= 0.0f) && (y0f + 1.0f < 23.0f);
                int xc0 = min(max(xi, 0), WV - 1), xc1 = min(max(xi + 1, 0), WV - 1);
                int yc0 = min(max(yi, 0), HV - 1), yc1 = min(max(yi + 1, 0), HV - 1);
                float g00 = (vx0 && vy0) ? vb[(yc0 * WV + xc0) * C_ + t] : 0.0f;
                float g10 = (vx1 && vy0) ? vb[(yc0 * WV + xc1) * C_ + t] : 0.0f;
                float g01 = (vx0 && vy1) ? vb[(yc1 * WV + xc0) * C_ + t] : 0.0f;
                float g11 = (vx1 && vy1) ? vb[(yc1 * WV + xc1) * C_ + t] : 0.0f;
                float t00 = g00 * (wx0 * wy0);
                float t10 = g10 * (wx1 * wy0);
                float t01 = g01 * (wx0 * wy1);
                float t11 = g11 * (wx1 * wy1);
                float samp = ((t00 + t10) + t01) + t11;
                float pr = s_attn[h * 4 + p] * samp;
                acc = acc + pr;
            }
            out_l[v][t] = acc;
        }
        __syncthreads();

        float bacc[NV];
        #pragma unroll
        for (int v = 0; v < NV; ++v) bacc[v] = 0.f;
        for (int i2 = 0; i2 < C_; ++i2) {
            float w_it = Wout[i2 * C_ + t];
            #pragma unroll
            for (int v = 0; v < NV; ++v) bacc[v] = __builtin_fmaf(out_l[v][i2], w_it, bacc[v]);
        }
        float bo_t = bout[t];
        float qv = query[(size_t)row * C_ + t];
        #pragma unroll
        for (int v = 0; v < NV; ++v) bevs_l[v][t] = (bacc[v] + bo_t) + qv;
        __syncthreads();

        if (t < NV) {
            float lv = 0.f;
            for (int c = 0; c < C_; ++c) lv = __builtin_fmaf(bevs_l[t][c], wp_lds[c], lv);
            lgs[t] = lv + bp[0];
        }
        __syncthreads();

        if (t == 0) {
            float l[NV];
            #pragma unroll
            for (int v = 0; v < NV; ++v) l[v] = lgs[v];
            float m = l[0];
            #pragma unroll
            for (int v = 1; v < NV; ++v) m = fmaxf(m, l[v]);
            float e[NV];
            #pragma unroll
            for (int v = 0; v < NV; ++v) e[v] = expf(l[v] - m);
            float s = ((e[0] + e[1]) + (e[2] + e[3])) + ((e[4] + e[5]) + (e[6] + e[7]));
            float w[NV];
            #pragma unroll
            for (int v = 0; v < NV; ++v) w[v] = e[v] / s;
            int am = 0; float wm = w[0];
            #pragma unroll
            for (int v = 1; v < NV; ++v) { if (w[v] > wm) { wm = w[v]; am = v; } }
            amax_out[row] = (float)am;
        }
        __syncthreads();
    }
}

extern "C" void kernel_launch(void* const* d_in, const int* in_sizes, int n_in,
                              void* d_out, int out_size, void* d_ws, size_t ws_size,
                              hipStream_t stream) {
    const float* query   = (const float*)d_in[0];
    const float* value   = (const float*)d_in[1];
    const float* grd_col = (const float*)d_in[2];
    const float* grd_row = (const float*)d_in[3];
    const float* Wv      = (const float*)d_in[4];
    const float* bv      = (const float*)d_in[5];
    const float* Wo      = (const float*)d_in[6];
    const float* bo      = (const float*)d_in[7];
    const float* Wa      = (const float*)d_in[8];
    const float* ba      = (const float*)d_in[9];
    const float* Wout    = (const float*)d_in[10];
    const float* bout    = (const float*)d_in[11];
    const float* Wp      = (const float*)d_in[12];
    const float* bp      = (const float*)d_in[13];

    float* out  = (float*)d_out;
    float* ws   = (float*)d_ws;
    float* offn = ws;                                        // 32768*64 f32
    float* attn = offn + (size_t)NROW * 64;                  // 32768*32 f32
    float* v2d  = attn + (size_t)NROW * 32;                  // 8464*256 f32
    float* wp2f = v2d + (size_t)BS * NPIX * C_;              // 256 f32
    float* S32  = wp2f + C_;                                 // 8464*8 f32
    int* cnt    = (int*)(S32 + (size_t)BS * NPIX * HEADS);   // 1 int (padded to 4 -> VW 16B-aligned)
    int* list   = cnt + 4;                                   // 32768 int
    ushort_t* VW = (ushort_t*)(list + NROW);                 // 8464*256 fp16
    float* WvWout = (float*)(VW + (size_t)BS * NPIX * C_);   // 256*256 f32
    float* bvW    = WvWout + C_ * C_;                        // 256 f32
    float* amax = out + (size_t)NROW * C_;

    prep_kernel<<<65, 256, 0, stream>>>(Wout, Wp, Wv, bv, WvWout, wp2f, bvW, cnt);
    proj_kernel<<<NVBLK2 + NQBLK, 256, 0, stream>>>(value, Wv, bv, WvWout, bvW, wp2f,
                                                    query, Wo, bo, Wa, ba,
                                                    v2d, VW, S32, offn, attn);
    fused_kernel<<<NROW, 256, 0, stream>>>(VW, offn, attn, grd_col, grd_row, S32,
                                           query, bout, out, amax, cnt, list);
    exact_kernel<<<512, 256, 0, stream>>>(v2d, offn, attn, grd_col, grd_row,
                                          Wout, bout, Wp, bp, query, cnt, list, amax);
}

// Round 10
// 221.869 us; speedup vs baseline: 1.0879x; 1.0108x over previous
//
#include <hip/hip_runtime.h>
#include <hip/hip_fp16.h>

#define NV 8
#define NQ 4096
#define C_ 256
#define HEADS 8
#define PTS 4
#define HV 23
#define WV 46
#define NPIX (HV*WV)       // 1058
#define BS 8
#define NROW (BS*NQ)       // 32768
#define NVBLK2 ((BS*NPIX)/16) // 529 value blocks (16 rows each)
#define NQBLK (NROW/16)       // 2048 query blocks

typedef unsigned short ushort_t;
typedef unsigned int uint_t;

// ---------------- prep (65 blocks): 0..63 WvWout = Wv@Wout; 64: wp2f = Wout@Wp, bvW = bv@Wout, cnt=0 ----------------
__global__ void prep_kernel(const float* __restrict__ Wout, const float* __restrict__ Wp,
                            const float* __restrict__ Wv, const float* __restrict__ bv,
                            float* __restrict__ WvWout, float* __restrict__ wp2f,
                            float* __restrict__ bvW, int* __restrict__ cnt) {
    int blk = blockIdx.x;
    int t = threadIdx.x;
    __shared__ float rows[4][C_];
    if (blk < 64) {
        int r0 = blk * 4;
        #pragma unroll
        for (int r = 0; r < 4; ++r) rows[r][t] = Wv[(r0 + r) * C_ + t];
        __syncthreads();
        float acc[4] = {0.f, 0.f, 0.f, 0.f};
        for (int k = 0; k < C_; ++k) {
            float w = Wout[k * C_ + t];
            acc[0] = fmaf(rows[0][k], w, acc[0]);
            acc[1] = fmaf(rows[1][k], w, acc[1]);
            acc[2] = fmaf(rows[2][k], w, acc[2]);
            acc[3] = fmaf(rows[3][k], w, acc[3]);
        }
        #pragma unroll
        for (int r = 0; r < 4; ++r) WvWout[(r0 + r) * C_ + t] = acc[r];
    } else {
        if (t == 0) *cnt = 0;
        float a = 0.f;
        for (int c = 0; c < C_; ++c) a = fmaf(Wout[t * C_ + c], Wp[c], a);
        wp2f[t] = a;
        float fb = 0.f;
        for (int d = 0; d < C_; ++d) fb = fmaf(bv[d], Wout[d * C_ + t], fb);
        bvW[t] = fb;
    }
}

// ---------------- proj: value blocks (16 rows, one k-loop: v2d exact + VW) + paired S32P; query blocks ----------------
// R2-verified structure. S32 now stored PAIRED: S32P[row][h] = float2(S[row][h], S[row+1][h])
// so fused reads 2x8B instead of 4x4B (TA request cut). Values identical -> logits bit-identical.
__global__ void proj_kernel(const float* __restrict__ value, const float* __restrict__ Wv,
                            const float* __restrict__ bv, const float* __restrict__ WvWout,
                            const float* __restrict__ bvW, const float* __restrict__ wp2f,
                            const float* __restrict__ query,
                            const float* __restrict__ Wo, const float* __restrict__ bo,
                            const float* __restrict__ Wa, const float* __restrict__ ba,
                            float* __restrict__ v2d, ushort_t* __restrict__ VW,
                            float* __restrict__ S32P, float* __restrict__ offn,
                            float* __restrict__ attn) {
#pragma clang fp contract(off)
    __shared__ float sbuf[16 * C_ + 16 * 32];
    int blk = blockIdx.x;
    int t = threadIdx.x;
    if (blk < NVBLK2) {
        // ===== value part: 16 rows/block, single k-loop, 32 accumulator chains =====
        float (*rows)[C_] = (float (*)[C_])sbuf;             // [16][256] value rows
        int r0 = blk * 16;
        #pragma unroll
        for (int i = 0; i < 16; ++i) {
            int idx = t + i * 256;
            rows[idx >> 8][idx & 255] = value[(size_t)r0 * C_ + idx];
        }
        __syncthreads();
        float acc[16], accW[16];
        #pragma unroll
        for (int r = 0; r < 16; ++r) { acc[r] = 0.f; accW[r] = 0.f; }
        for (int k4 = 0; k4 < C_ / 4; ++k4) {
            int k = k4 * 4;
            float w0 = Wv[(k + 0) * C_ + t], w1 = Wv[(k + 1) * C_ + t];
            float w2 = Wv[(k + 2) * C_ + t], w3 = Wv[(k + 3) * C_ + t];
            float u0 = WvWout[(k + 0) * C_ + t], u1 = WvWout[(k + 1) * C_ + t];
            float u2 = WvWout[(k + 2) * C_ + t], u3 = WvWout[(k + 3) * C_ + t];
            #pragma unroll
            for (int r = 0; r < 16; ++r) {
                const float4 qv = *(reinterpret_cast<const float4*>(rows[r]) + k4);
                acc[r] = __builtin_fmaf(qv.x, w0, acc[r]);   // exact: sequential k order
                acc[r] = __builtin_fmaf(qv.y, w1, acc[r]);
                acc[r] = __builtin_fmaf(qv.z, w2, acc[r]);
                acc[r] = __builtin_fmaf(qv.w, w3, acc[r]);
                accW[r] = fmaf(qv.x, u0, accW[r]);
                accW[r] = fmaf(qv.y, u1, accW[r]);
                accW[r] = fmaf(qv.z, u2, accW[r]);
                accW[r] = fmaf(qv.w, u3, accW[r]);
            }
        }
        float b = bv[t];
        float b2 = bvW[t];
        #pragma unroll
        for (int r = 0; r < 16; ++r) {
            acc[r] = acc[r] + b;   // vd
            v2d[(size_t)(r0 + r) * C_ + t] = acc[r];
            VW[(size_t)(r0 + r) * C_ + t] = __half_as_ushort(__float2half(accW[r] + b2));
        }
        // S32P[row][head] paired: .x at own slot, .y at slot row-1 (same batch only)
        float wpt = wp2f[t];
        #pragma unroll
        for (int r = 0; r < 16; ++r) {
            float p = acc[r] * wpt;
            p += __shfl_down(p, 16, 32);
            p += __shfl_down(p, 8, 32);
            p += __shfl_down(p, 4, 32);
            p += __shfl_down(p, 2, 32);
            p += __shfl_down(p, 1, 32);
            if ((t & 31) == 0) {
                int row = r0 + r;
                int h = t >> 5;
                S32P[((size_t)row * HEADS + h) * 2] = p;             // slot[row].x = S[row]
                int pix = row - (row / NPIX) * NPIX;
                if (pix > 0)
                    S32P[((size_t)(row - 1) * HEADS + h) * 2 + 1] = p; // slot[row-1].y = S[row]
            }
        }
    } else {
        // ===== query part: 16 rows/block, two independent 128-thread halves, float4 LDS =====
        int qb = blk - NVBLK2;
        int half = t >> 7, tt = t & 127;
        int rb = qb * 16 + half * 8;
        float (*qs)[C_] = (float (*)[C_])sbuf;
        float (*lg)[32] = (float (*)[32])(sbuf + 16 * C_);
        #pragma unroll
        for (int i = 0; i < 16; ++i) {
            int idx = tt + i * 128;
            int rr = idx >> 8, cc = idx & 255;
            qs[half * 8 + rr][cc] = query[(size_t)(rb + rr) * C_ + cc];
        }
        __syncthreads();
        if (tt < 64) {
            float acc[8] = {0.f, 0.f, 0.f, 0.f, 0.f, 0.f, 0.f, 0.f};
            for (int k4 = 0; k4 < C_ / 4; ++k4) {
                int k = k4 * 4;
                float w0 = Wo[(k + 0) * 64 + tt], w1 = Wo[(k + 1) * 64 + tt];
                float w2 = Wo[(k + 2) * 64 + tt], w3 = Wo[(k + 3) * 64 + tt];
                #pragma unroll
                for (int r = 0; r < 8; ++r) {
                    const float4 qv = *(reinterpret_cast<const float4*>(qs[half * 8 + r]) + k4);
                    acc[r] = __builtin_fmaf(qv.x, w0, acc[r]);
                    acc[r] = __builtin_fmaf(qv.y, w1, acc[r]);
                    acc[r] = __builtin_fmaf(qv.z, w2, acc[r]);
                    acc[r] = __builtin_fmaf(qv.w, w3, acc[r]);
                }
            }
            float b = bo[tt];
            float nrm = (tt & 1) ? 23.0f : 46.0f;
            #pragma unroll
            for (int r = 0; r < 8; ++r) offn[(size_t)(rb + r) * 64 + tt] = (acc[r] + b) / nrm;
        } else if (tt < 96) {
            int j = tt - 64;
            float acc[8] = {0.f, 0.f, 0.f, 0.f, 0.f, 0.f, 0.f, 0.f};
            for (int k4 = 0; k4 < C_ / 4; ++k4) {
                int k = k4 * 4;
                float w0 = Wa[(k + 0) * 32 + j], w1 = Wa[(k + 1) * 32 + j];
                float w2 = Wa[(k + 2) * 32 + j], w3 = Wa[(k + 3) * 32 + j];
                #pragma unroll
                for (int r = 0; r < 8; ++r) {
                    const float4 qv = *(reinterpret_cast<const float4*>(qs[half * 8 + r]) + k4);
                    acc[r] = __builtin_fmaf(qv.x, w0, acc[r]);
                    acc[r] = __builtin_fmaf(qv.y, w1, acc[r]);
                    acc[r] = __builtin_fmaf(qv.z, w2, acc[r]);
                    acc[r] = __builtin_fmaf(qv.w, w3, acc[r]);
                }
            }
            float b = ba[j];
            #pragma unroll
            for (int r = 0; r < 8; ++r) lg[half * 8 + r][j] = acc[r] + b;
        }
        __syncthreads();
        if (tt < 64) {
            int r = tt >> 3, h = tt & 7;
            int lr = half * 8 + r;
            float v0 = lg[lr][h * 4 + 0], v1 = lg[lr][h * 4 + 1];
            float v2 = lg[lr][h * 4 + 2], v3 = lg[lr][h * 4 + 3];
            float m = fmaxf(fmaxf(fmaxf(v0, v1), v2), v3);
            float e0 = expf(v0 - m), e1 = expf(v1 - m), e2 = expf(v2 - m), e3 = expf(v3 - m);
            float s = ((e0 + e1) + e2) + e3;
            attn[(size_t)(rb + r) * 32 + h * 4 + 0] = e0 / s;
            attn[(size_t)(rb + r) * 32 + h * 4 + 1] = e1 / s;
            attn[(size_t)(rb + r) * 32 + h * 4 + 2] = e2 / s;
            attn[(size_t)(rb + r) * 32 + h * 4 + 3] = e3 / s;
        }
    }
}

// ---------------- fused: f32 gap-tested logits (paired S32P, 2x8B loads) + hfma2 sampling ----------------
__global__ void __launch_bounds__(256) fused_kernel(
        const ushort_t* __restrict__ VW, const float* __restrict__ offn,
        const float* __restrict__ attn, const float* __restrict__ grd_col,
        const float* __restrict__ grd_row, const float* __restrict__ S32P,
        const float* __restrict__ query, const float* __restrict__ bout,
        float* __restrict__ out, float* __restrict__ amax_out,
        int* __restrict__ cnt, int* __restrict__ list) {
    int bid = blockIdx.x;
    int row = ((bid & 7) << 12) | (bid >> 3);   // XCD-bijective: batch <-> XCD affinity
    int b = row >> 12;
    int q = row & (NQ - 1);
    int t = threadIdx.x;
    __shared__ __align__(16) int     g_ip[256][4];
    __shared__ __align__(16) __half2 g_wh[256][4];   // duplicated half2 per corner weight
    __shared__ __align__(16) float red[NV][C_];
    __shared__ float logits_sh[NV];
    __shared__ float wf_sh[NV];

    // ---- phase A (f32): t = v*32 + (h*4+p)
    {
        int v = t >> 5, r = t & 31, h = r >> 2;
        const float2 off2 = ((const float2*)(offn + (size_t)row * 64))[r];
        float at = attn[(size_t)row * 32 + r];
        float refx = grd_col[q * NV + v];
        float refy = grd_row[q * NV + v];
        float lx = refx + off2.x;
        float ly = refy + off2.y;
        float x = lx * 46.0f - 0.5f;
        float y = ly * 23.0f - 0.5f;
        float x0f = floorf(x), y0f = floorf(y);
        float wx1 = x - x0f, wy1 = y - y0f;
        float wx0 = 1.0f - wx1, wy0 = 1.0f - wy1;
        int xi = (int)x0f, yi = (int)y0f;
        bool vx0 = (x0f >= 0.0f) && (x0f < 46.0f);
        bool vx1 = (x0f + 1.0f >= 0.0f) && (x0f + 1.0f < 46.0f);
        bool vy0 = (y0f >= 0.0f) && (y0f < 23.0f);
        bool vy1 = (y0f + 1.0f >= 0.0f) && (y0f + 1.0f < 23.0f);
        int xc0 = min(max(xi, 0), WV - 1), xc1 = min(max(xi + 1, 0), WV - 1);
        int yc0 = min(max(yi, 0), HV - 1), yc1 = min(max(yi + 1, 0), HV - 1);
        float w00 = (vx0 && vy0) ? wx0 * wy0 : 0.0f;
        float w10 = (vx1 && vy0) ? wx1 * wy0 : 0.0f;
        float w01 = (vx0 && vy1) ? wx0 * wy1 : 0.0f;
        float w11 = (vx1 && vy1) ? wx1 * wy1 : 0.0f;
        int ip00 = yc0 * WV + xc0, ip10 = yc0 * WV + xc1;
        int ip01 = yc1 * WV + xc0, ip11 = yc1 * WV + xc1;

        g_ip[t][0] = ip00 * (C_ * 2); g_ip[t][1] = ip10 * (C_ * 2);   // byte offsets
        g_ip[t][2] = ip01 * (C_ * 2); g_ip[t][3] = ip11 * (C_ * 2);
        __half hw0 = __float2half(w00 * at);
        __half hw1 = __float2half(w10 * at);
        __half hw2 = __float2half(w01 * at);
        __half hw3 = __float2half(w11 * at);
        g_wh[t][0] = __halves2half2(hw0, hw0);
        g_wh[t][1] = __halves2half2(hw1, hw1);
        g_wh[t][2] = __halves2half2(hw2, hw2);
        g_wh[t][3] = __halves2half2(hw3, hw3);

        // paired S32 loads: slot[ip] = (S[ip], S[ip+1]); ip10 in {ip00, ip00+1}
        const float2* Sb = (const float2*)S32P + (size_t)b * NPIX * HEADS;
        float2 s0 = Sb[ip00 * HEADS + h];
        float2 s1 = Sb[ip01 * HEADS + h];
        float s10 = (ip10 == ip00) ? s0.x : s0.y;
        float s11 = (ip11 == ip01) ? s1.x : s1.y;
        float samp = w00 * s0.x + w10 * s10 + w01 * s1.x + w11 * s11;
        float contrib = at * samp;
        #pragma unroll
        for (int s2 = 16; s2; s2 >>= 1) contrib += __shfl_down(contrib, s2, 32);
        if (r == 0) logits_sh[v] = contrib;
    }
    __syncthreads();                                   // barrier 1 (A -> B)

    // ---- lanes 0..7 (f32): argmax + gap test + softmax weights
    if (t < 8) {
        float m = logits_sh[0]; int am = 0;
        #pragma unroll
        for (int v2 = 1; v2 < NV; ++v2) {
            float lv = logits_sh[v2];
            if (lv > m) { m = lv; am = v2; }
        }
        float e = expf(logits_sh[t] - m);
        float ssum = e;
        ssum += __shfl_xor(ssum, 1, 8);
        ssum += __shfl_xor(ssum, 2, 8);
        ssum += __shfl_xor(ssum, 4, 8);
        wf_sh[t] = e / ssum;
        if (t == 0) {
            amax_out[row] = (float)am;
            float m2 = -1e30f;
            #pragma unroll
            for (int v2 = 0; v2 < NV; ++v2) {
                float lv = logits_sh[v2];
                if (v2 != am && lv > m2) m2 = lv;
            }
            float thr = 1e-4f * fmaxf(1.0f, fabsf(m));
            if ((m - m2) < thr) {
                int idx = atomicAdd(cnt, 1);
                list[idx] = row;
            }
        }
    }

    // ---- phase B: 8 groups x 32 threads; group g = v; 8 channels/thread; packed f16 FMA
    {
        int g = t >> 5, lt = t & 31;
        int c0 = lt * 8;
        int c2 = c0 * 2;               // channel byte offset
        int hb = lt >> 2;
        const char* vb = (const char*)(VW + (size_t)b * NPIX * C_);
        __half2 h01 = __float2half2_rn(0.f);
        __half2 h23 = h01, h45 = h01, h67 = h01;
        #pragma unroll
        for (int pp = 0; pp < 2; ++pp) {
            int e0 = g * 32 + hb * 4 + pp * 2;         // entry (v=g, h=hb, p=pp*2); +1 -> p+1
            const int4   ipA = *reinterpret_cast<const int4*>(g_ip[e0]);
            const uint4  whA = *reinterpret_cast<const uint4*>(g_wh[e0]);
            const int4   ipB = *reinterpret_cast<const int4*>(g_ip[e0 + 1]);
            const uint4  whB = *reinterpret_cast<const uint4*>(g_wh[e0 + 1]);
            const uint4 uA0 = *reinterpret_cast<const uint4*>(vb + (ipA.x + c2));
            const uint4 uA1 = *reinterpret_cast<const uint4*>(vb + (ipA.y + c2));
            const uint4 uA2 = *reinterpret_cast<const uint4*>(vb + (ipA.z + c2));
            const uint4 uA3 = *reinterpret_cast<const uint4*>(vb + (ipA.w + c2));
            const uint4 uB0 = *reinterpret_cast<const uint4*>(vb + (ipB.x + c2));
            const uint4 uB1 = *reinterpret_cast<const uint4*>(vb + (ipB.y + c2));
            const uint4 uB2 = *reinterpret_cast<const uint4*>(vb + (ipB.z + c2));
            const uint4 uB3 = *reinterpret_cast<const uint4*>(vb + (ipB.w + c2));
            #define CORNER(WHU, U) { \
                const __half2 wh = *reinterpret_cast<const __half2*>(&WHU); \
                h01 = __hfma2(wh, *reinterpret_cast<const __half2*>(&U.x), h01); \
                h23 = __hfma2(wh, *reinterpret_cast<const __half2*>(&U.y), h23); \
                h45 = __hfma2(wh, *reinterpret_cast<const __half2*>(&U.z), h45); \
                h67 = __hfma2(wh, *reinterpret_cast<const __half2*>(&U.w), h67); }
            CORNER(whA.x, uA0)
            CORNER(whA.y, uA1)
            CORNER(whA.z, uA2)
            CORNER(whA.w, uA3)
            CORNER(whB.x, uB0)
            CORNER(whB.y, uB1)
            CORNER(whB.z, uB2)
            CORNER(whB.w, uB3)
            #undef CORNER
        }
        float a0 = __low2float(h01), a1 = __high2float(h01);
        float a2 = __low2float(h23), a3 = __high2float(h23);
        float a4 = __low2float(h45), a5 = __high2float(h45);
        float a6 = __low2float(h67), a7 = __high2float(h67);
        float4 s0v = {a0, a1, a2, a3}, s1v = {a4, a5, a6, a7};
        *reinterpret_cast<float4*>(&red[g][c0])     = s0v;
        *reinterpret_cast<float4*>(&red[g][c0 + 4]) = s1v;
    }
    __syncthreads();                                   // barrier 2 (B -> epilogue)
    float O = 0.f;
    #pragma unroll
    for (int g8 = 0; g8 < NV; ++g8) O = fmaf(wf_sh[g8], red[g8][t], O);
    out[(size_t)row * C_ + t] = O + bout[t] + 2.0f * query[(size_t)row * C_ + t];
}

// ---------------- exact replication (compacted: grid-stride over flagged list) ----------------
__global__ void __launch_bounds__(256) exact_kernel(
        const float* __restrict__ v2d, const float* __restrict__ offn,
        const float* __restrict__ attn, const float* __restrict__ grd_col,
        const float* __restrict__ grd_row, const float* __restrict__ Wout,
        const float* __restrict__ bout, const float* __restrict__ Wp,
        const float* __restrict__ bp, const float* __restrict__ query,
        const int* __restrict__ cnt, const int* __restrict__ list,
        float* __restrict__ amax_out) {
#pragma clang fp contract(off)
    int n = *cnt;
    int t = threadIdx.x;
    int h = t >> 5;
    __shared__ float s_off[64];
    __shared__ float s_attn[32];
    __shared__ float wp_lds[C_];
    __shared__ float out_l[NV][C_ + 1];
    __shared__ float bevs_l[NV][C_ + 1];
    __shared__ float lgs[NV];
    wp_lds[t] = Wp[t];

    for (int i = blockIdx.x; i < n; i += gridDim.x) {
        int row = list[i];
        int b = row >> 12;
        int q = row & (NQ - 1);
        if (t < 64)      s_off[t]       = offn[(size_t)row * 64 + t];
        else if (t < 96) s_attn[t - 64] = attn[(size_t)row * 32 + (t - 64)];
        __syncthreads();

        const float* vb = v2d + (size_t)b * NPIX * C_;
        #pragma unroll
        for (int v = 0; v < NV; ++v) {
            float refx = grd_col[q * NV + v];
            float refy = grd_row[q * NV + v];
            float acc = 0.0f;
            #pragma unroll
            for (int p = 0; p < PTS; ++p) {
                float lx = refx + s_off[h * 8 + p * 2 + 0];
                float ly = refy + s_off[h * 8 + p * 2 + 1];
                float x = lx * 46.0f - 0.5f;
                float y = ly * 23.0f - 0.5f;
                float x0f = floorf(x), y0f = floorf(y);
                float wx1 = x - x0f, wy1 = y - y0f;
                float wx0 = 1.0f - wx1, wy0 = 1.0f - wy1;
                int xi = (int)x0f, yi = (int)y0f;
                bool vx0 = (x0f >= 0.0f) && (x0f < 46.0f);
                bool vx1 = (x0f + 1.0f >= 0.0f) && (x0f + 1.0f < 46.0f);
                bool vy0 = (y0f >= 0.0f) && (y0f < 23.0f);
                bool vy1 = (y0f + 1.0f >= 0.0f) && (y0f + 1.0f < 23.0f);
                int xc0 = min(max(xi, 0), WV - 1), xc1 = min(max(xi + 1, 0), WV - 1);
                int yc0 = min(max(yi, 0), HV - 1), yc1 = min(max(yi + 1, 0), HV - 1);
                float g00 = (vx0 && vy0) ? vb[(yc0 * WV + xc0) * C_ + t] : 0.0f;
                float g10 = (vx1 && vy0) ? vb[(yc0 * WV + xc1) * C_ + t] : 0.0f;
                float g01 = (vx0 && vy1) ? vb[(yc1 * WV + xc0) * C_ + t] : 0.0f;
                float g11 = (vx1 && vy1) ? vb[(yc1 * WV + xc1) * C_ + t] : 0.0f;
                float t00 = g00 * (wx0 * wy0);
                float t10 = g10 * (wx1 * wy0);
                float t01 = g01 * (wx0 * wy1);
                float t11 = g11 * (wx1 * wy1);
                float samp = ((t00 + t10) + t01) + t11;
                float pr = s_attn[h * 4 + p] * samp;
                acc = acc + pr;
            }
            out_l[v][t] = acc;
        }
        __syncthreads();

        float bacc[NV];
        #pragma unroll
        for (int v = 0; v < NV; ++v) bacc[v] = 0.f;
        for (int i2 = 0; i2 < C_; ++i2) {
            float w_it = Wout[i2 * C_ + t];
            #pragma unroll
            for (int v = 0; v < NV; ++v) bacc[v] = __builtin_fmaf(out_l[v][i2], w_it, bacc[v]);
        }
        float bo_t = bout[t];
        float qv = query[(size_t)row * C_ + t];
        #pragma unroll
        for (int v = 0; v < NV; ++v) bevs_l[v][t] = (bacc[v] + bo_t) + qv;
        __syncthreads();

        if (t < NV) {
            float lv = 0.f;
            for (int c = 0; c < C_; ++c) lv = __builtin_fmaf(bevs_l[t][c], wp_lds[c], lv);
            lgs[t] = lv + bp[0];
        }
        __syncthreads();

        if (t == 0) {
            float l[NV];
            #pragma unroll
            for (int v = 0; v < NV; ++v) l[v] = lgs[v];
            float m = l[0];
            #pragma unroll
            for (int v = 1; v < NV; ++v) m = fmaxf(m, l[v]);
            float e[NV];
            #pragma unroll
            for (int v = 0; v < NV; ++v) e[v] = expf(l[v] - m);
            float s = ((e[0] + e[1]) + (e[2] + e[3])) + ((e[4] + e[5]) + (e[6] + e[7]));
            float w[NV];
            #pragma unroll
            for (int v = 0; v < NV; ++v) w[v] = e[v] / s;
            int am = 0; float wm = w[0];
            #pragma unroll
            for (int v = 1; v < NV; ++v) { if (w[v] > wm) { wm = w[v]; am = v; } }
            amax_out[row] = (float)am;
        }
        __syncthreads();
    }
}

extern "C" void kernel_launch(void* const* d_in, const int* in_sizes, int n_in,
                              void* d_out, int out_size, void* d_ws, size_t ws_size,
                              hipStream_t stream) {
    const float* query   = (const float*)d_in[0];
    const float* value   = (const float*)d_in[1];
    const float* grd_col = (const float*)d_in[2];
    const float* grd_row = (const float*)d_in[3];
    const float* Wv      = (const float*)d_in[4];
    const float* bv      = (const float*)d_in[5];
    const float* Wo      = (const float*)d_in[6];
    const float* bo      = (const float*)d_in[7];
    const float* Wa      = (const float*)d_in[8];
    const float* ba      = (const float*)d_in[9];
    const float* Wout    = (const float*)d_in[10];
    const float* bout    = (const float*)d_in[11];
    const float* Wp      = (const float*)d_in[12];
    const float* bp      = (const float*)d_in[13];

    float* out  = (float*)d_out;
    float* ws   = (float*)d_ws;
    float* offn = ws;                                        // 32768*64 f32
    float* attn = offn + (size_t)NROW * 64;                  // 32768*32 f32
    float* v2d  = attn + (size_t)NROW * 32;                  // 8464*256 f32
    float* wp2f = v2d + (size_t)BS * NPIX * C_;              // 256 f32
    float* S32P = wp2f + C_;                                 // 8464*8 float2 = 135424 f32
    int* cnt    = (int*)(S32P + (size_t)BS * NPIX * HEADS * 2); // 1 int (padded to 4)
    int* list   = cnt + 4;                                   // 32768 int
    ushort_t* VW = (ushort_t*)(list + NROW);                 // 8464*256 fp16
    float* WvWout = (float*)(VW + (size_t)BS * NPIX * C_);   // 256*256 f32
    float* bvW    = WvWout + C_ * C_;                        // 256 f32
    float* amax = out + (size_t)NROW * C_;

    prep_kernel<<<65, 256, 0, stream>>>(Wout, Wp, Wv, bv, WvWout, wp2f, bvW, cnt);
    proj_kernel<<<NVBLK2 + NQBLK, 256, 0, stream>>>(value, Wv, bv, WvWout, bvW, wp2f,
                                                    query, Wo, bo, Wa, ba,
                                                    v2d, VW, S32P, offn, attn);
    fused_kernel<<<NROW, 256, 0, stream>>>(VW, offn, attn, grd_col, grd_row, S32P,
                                           query, bout, out, amax, cnt, list);
    exact_kernel<<<512, 256, 0, stream>>>(v2d, offn, attn, grd_col, grd_row,
                                          Wout, bout, Wp, bp, query, cnt, list, amax);
}

// Round 11
// 219.656 us; speedup vs baseline: 1.0989x; 1.0101x over previous
//
#include <hip/hip_runtime.h>
#include <hip/hip_fp16.h>

#define NV 8
#define NQ 4096
#define C_ 256
#define HEADS 8
#define PTS 4
#define HV 23
#define WV 46
#define NPIX (HV*WV)       // 1058
#define BS 8
#define NROW (BS*NQ)       // 32768
#define NVBLK2 ((BS*NPIX)/16) // 529 value blocks (16 rows each)
#define NQBLK (NROW/16)       // 2048 query blocks

typedef unsigned short ushort_t;
typedef unsigned int uint_t;

// ---------------- prep (65 blocks): 0..63 WvWout = Wv@Wout; 64: wp2f = Wout@Wp, bvW = bv@Wout, cnt=0 ----------------
__global__ void prep_kernel(const float* __restrict__ Wout, const float* __restrict__ Wp,
                            const float* __restrict__ Wv, const float* __restrict__ bv,
                            float* __restrict__ WvWout, float* __restrict__ wp2f,
                            float* __restrict__ bvW, int* __restrict__ cnt) {
    int blk = blockIdx.x;
    int t = threadIdx.x;
    __shared__ float rows[4][C_];
    if (blk < 64) {
        int r0 = blk * 4;
        #pragma unroll
        for (int r = 0; r < 4; ++r) rows[r][t] = Wv[(r0 + r) * C_ + t];
        __syncthreads();
        float acc[4] = {0.f, 0.f, 0.f, 0.f};
        for (int k = 0; k < C_; ++k) {
            float w = Wout[k * C_ + t];
            acc[0] = fmaf(rows[0][k], w, acc[0]);
            acc[1] = fmaf(rows[1][k], w, acc[1]);
            acc[2] = fmaf(rows[2][k], w, acc[2]);
            acc[3] = fmaf(rows[3][k], w, acc[3]);
        }
        #pragma unroll
        for (int r = 0; r < 4; ++r) WvWout[(r0 + r) * C_ + t] = acc[r];
    } else {
        if (t == 0) *cnt = 0;
        float a = 0.f;
        for (int c = 0; c < C_; ++c) a = fmaf(Wout[t * C_ + c], Wp[c], a);
        wp2f[t] = a;
        float fb = 0.f;
        for (int d = 0; d < C_; ++d) fb = fmaf(bv[d], Wout[d * C_ + t], fb);
        bvW[t] = fb;
    }
}

// ---------------- proj: value blocks (16 rows, one k-loop: v2d exact + VW) + quad S32Q; query blocks ----------------
// S32 stored QUAD: S32Q[row][h] = float4(S[pix], S[pix+1], S[pix+WV], S[pix+WV+1])
// so fused reads ONE 16B load per (v,h). Values identical -> logits bit-identical.
__global__ void proj_kernel(const float* __restrict__ value, const float* __restrict__ Wv,
                            const float* __restrict__ bv, const float* __restrict__ WvWout,
                            const float* __restrict__ bvW, const float* __restrict__ wp2f,
                            const float* __restrict__ query,
                            const float* __restrict__ Wo, const float* __restrict__ bo,
                            const float* __restrict__ Wa, const float* __restrict__ ba,
                            float* __restrict__ v2d, ushort_t* __restrict__ VW,
                            float* __restrict__ S32Q, float* __restrict__ offn,
                            float* __restrict__ attn) {
#pragma clang fp contract(off)
    __shared__ float sbuf[16 * C_ + 16 * 32];
    int blk = blockIdx.x;
    int t = threadIdx.x;
    if (blk < NVBLK2) {
        // ===== value part: 16 rows/block, single k-loop, 32 accumulator chains =====
        float (*rows)[C_] = (float (*)[C_])sbuf;             // [16][256] value rows
        int r0 = blk * 16;
        #pragma unroll
        for (int i = 0; i < 16; ++i) {
            int idx = t + i * 256;
            rows[idx >> 8][idx & 255] = value[(size_t)r0 * C_ + idx];
        }
        __syncthreads();
        float acc[16], accW[16];
        #pragma unroll
        for (int r = 0; r < 16; ++r) { acc[r] = 0.f; accW[r] = 0.f; }
        for (int k4 = 0; k4 < C_ / 4; ++k4) {
            int k = k4 * 4;
            float w0 = Wv[(k + 0) * C_ + t], w1 = Wv[(k + 1) * C_ + t];
            float w2 = Wv[(k + 2) * C_ + t], w3 = Wv[(k + 3) * C_ + t];
            float u0 = WvWout[(k + 0) * C_ + t], u1 = WvWout[(k + 1) * C_ + t];
            float u2 = WvWout[(k + 2) * C_ + t], u3 = WvWout[(k + 3) * C_ + t];
            #pragma unroll
            for (int r = 0; r < 16; ++r) {
                const float4 qv = *(reinterpret_cast<const float4*>(rows[r]) + k4);
                acc[r] = __builtin_fmaf(qv.x, w0, acc[r]);   // exact: sequential k order
                acc[r] = __builtin_fmaf(qv.y, w1, acc[r]);
                acc[r] = __builtin_fmaf(qv.z, w2, acc[r]);
                acc[r] = __builtin_fmaf(qv.w, w3, acc[r]);
                accW[r] = fmaf(qv.x, u0, accW[r]);
                accW[r] = fmaf(qv.y, u1, accW[r]);
                accW[r] = fmaf(qv.z, u2, accW[r]);
                accW[r] = fmaf(qv.w, u3, accW[r]);
            }
        }
        float b = bv[t];
        float b2 = bvW[t];
        #pragma unroll
        for (int r = 0; r < 16; ++r) {
            acc[r] = acc[r] + b;   // vd
            v2d[(size_t)(r0 + r) * C_ + t] = acc[r];
            VW[(size_t)(r0 + r) * C_ + t] = __half_as_ushort(__float2half(accW[r] + b2));
        }
        // S32Q scatter: each S[row] lands at slot[row].x, slot[row-1].y, slot[row-WV].z, slot[row-WV-1].w
        float wpt = wp2f[t];
        #pragma unroll
        for (int r = 0; r < 16; ++r) {
            float p = acc[r] * wpt;
            p += __shfl_down(p, 16, 32);
            p += __shfl_down(p, 8, 32);
            p += __shfl_down(p, 4, 32);
            p += __shfl_down(p, 2, 32);
            p += __shfl_down(p, 1, 32);
            if ((t & 31) == 0) {
                int row = r0 + r;
                int h = t >> 5;
                int pix = row - (row / NPIX) * NPIX;
                S32Q[((size_t)row * HEADS + h) * 4 + 0] = p;
                if (pix >= 1)
                    S32Q[((size_t)(row - 1) * HEADS + h) * 4 + 1] = p;
                if (pix >= WV)
                    S32Q[((size_t)(row - WV) * HEADS + h) * 4 + 2] = p;
                if (pix >= WV + 1)
                    S32Q[((size_t)(row - WV - 1) * HEADS + h) * 4 + 3] = p;
            }
        }
    } else {
        // ===== query part: 16 rows/block, two independent 128-thread halves, float4 LDS =====
        int qb = blk - NVBLK2;
        int half = t >> 7, tt = t & 127;
        int rb = qb * 16 + half * 8;
        float (*qs)[C_] = (float (*)[C_])sbuf;
        float (*lg)[32] = (float (*)[32])(sbuf + 16 * C_);
        #pragma unroll
        for (int i = 0; i < 16; ++i) {
            int idx = tt + i * 128;
            int rr = idx >> 8, cc = idx & 255;
            qs[half * 8 + rr][cc] = query[(size_t)(rb + rr) * C_ + cc];
        }
        __syncthreads();
        if (tt < 64) {
            float acc[8] = {0.f, 0.f, 0.f, 0.f, 0.f, 0.f, 0.f, 0.f};
            for (int k4 = 0; k4 < C_ / 4; ++k4) {
                int k = k4 * 4;
                float w0 = Wo[(k + 0) * 64 + tt], w1 = Wo[(k + 1) * 64 + tt];
                float w2 = Wo[(k + 2) * 64 + tt], w3 = Wo[(k + 3) * 64 + tt];
                #pragma unroll
                for (int r = 0; r < 8; ++r) {
                    const float4 qv = *(reinterpret_cast<const float4*>(qs[half * 8 + r]) + k4);
                    acc[r] = __builtin_fmaf(qv.x, w0, acc[r]);
                    acc[r] = __builtin_fmaf(qv.y, w1, acc[r]);
                    acc[r] = __builtin_fmaf(qv.z, w2, acc[r]);
                    acc[r] = __builtin_fmaf(qv.w, w3, acc[r]);
                }
            }
            float b = bo[tt];
            float nrm = (tt & 1) ? 23.0f : 46.0f;
            #pragma unroll
            for (int r = 0; r < 8; ++r) offn[(size_t)(rb + r) * 64 + tt] = (acc[r] + b) / nrm;
        } else if (tt < 96) {
            int j = tt - 64;
            float acc[8] = {0.f, 0.f, 0.f, 0.f, 0.f, 0.f, 0.f, 0.f};
            for (int k4 = 0; k4 < C_ / 4; ++k4) {
                int k = k4 * 4;
                float w0 = Wa[(k + 0) * 32 + j], w1 = Wa[(k + 1) * 32 + j];
                float w2 = Wa[(k + 2) * 32 + j], w3 = Wa[(k + 3) * 32 + j];
                #pragma unroll
                for (int r = 0; r < 8; ++r) {
                    const float4 qv = *(reinterpret_cast<const float4*>(qs[half * 8 + r]) + k4);
                    acc[r] = __builtin_fmaf(qv.x, w0, acc[r]);
                    acc[r] = __builtin_fmaf(qv.y, w1, acc[r]);
                    acc[r] = __builtin_fmaf(qv.z, w2, acc[r]);
                    acc[r] = __builtin_fmaf(qv.w, w3, acc[r]);
                }
            }
            float b = ba[j];
            #pragma unroll
            for (int r = 0; r < 8; ++r) lg[half * 8 + r][j] = acc[r] + b;
        }
        __syncthreads();
        if (tt < 64) {
            int r = tt >> 3, h = tt & 7;
            int lr = half * 8 + r;
            float v0 = lg[lr][h * 4 + 0], v1 = lg[lr][h * 4 + 1];
            float v2 = lg[lr][h * 4 + 2], v3 = lg[lr][h * 4 + 3];
            float m = fmaxf(fmaxf(fmaxf(v0, v1), v2), v3);
            float e0 = expf(v0 - m), e1 = expf(v1 - m), e2 = expf(v2 - m), e3 = expf(v3 - m);
            float s = ((e0 + e1) + e2) + e3;
            attn[(size_t)(rb + r) * 32 + h * 4 + 0] = e0 / s;
            attn[(size_t)(rb + r) * 32 + h * 4 + 1] = e1 / s;
            attn[(size_t)(rb + r) * 32 + h * 4 + 2] = e2 / s;
            attn[(size_t)(rb + r) * 32 + h * 4 + 3] = e3 / s;
        }
    }
}

// ---------------- fused: f32 gap-tested logits (quad S32Q, 1x16B load) + hfma2 sampling + epilogue prefetch ----------------
__global__ void __launch_bounds__(256) fused_kernel(
        const ushort_t* __restrict__ VW, const float* __restrict__ offn,
        const float* __restrict__ attn, const float* __restrict__ grd_col,
        const float* __restrict__ grd_row, const float* __restrict__ S32Q,
        const float* __restrict__ query, const float* __restrict__ bout,
        float* __restrict__ out, float* __restrict__ amax_out,
        int* __restrict__ cnt, int* __restrict__ list) {
    int bid = blockIdx.x;
    int row = ((bid & 7) << 12) | (bid >> 3);   // XCD-bijective: batch <-> XCD affinity
    int b = row >> 12;
    int q = row & (NQ - 1);
    int t = threadIdx.x;
    __shared__ __align__(16) int     g_ip[256][4];
    __shared__ __align__(16) __half2 g_wh[256][4];   // duplicated half2 per corner weight
    __shared__ __align__(16) float red[NV][C_];
    __shared__ float logits_sh[NV];
    __shared__ float wf_sh[NV];

    // epilogue prefetch: issue early so L2/HBM latency hides under phases A/B
    float q_pre = query[(size_t)row * C_ + t];
    float b_pre = bout[t];

    // ---- phase A (f32): t = v*32 + (h*4+p)
    {
        int v = t >> 5, r = t & 31, h = r >> 2;
        const float2 off2 = ((const float2*)(offn + (size_t)row * 64))[r];
        float at = attn[(size_t)row * 32 + r];
        float refx = grd_col[q * NV + v];
        float refy = grd_row[q * NV + v];
        float lx = refx + off2.x;
        float ly = refy + off2.y;
        float x = lx * 46.0f - 0.5f;
        float y = ly * 23.0f - 0.5f;
        float x0f = floorf(x), y0f = floorf(y);
        float wx1 = x - x0f, wy1 = y - y0f;
        float wx0 = 1.0f - wx1, wy0 = 1.0f - wy1;
        int xi = (int)x0f, yi = (int)y0f;
        bool vx0 = (x0f >= 0.0f) && (x0f < 46.0f);
        bool vx1 = (x0f + 1.0f >= 0.0f) && (x0f + 1.0f < 46.0f);
        bool vy0 = (y0f >= 0.0f) && (y0f < 23.0f);
        bool vy1 = (y0f + 1.0f >= 0.0f) && (y0f + 1.0f < 23.0f);
        int xc0 = min(max(xi, 0), WV - 1), xc1 = min(max(xi + 1, 0), WV - 1);
        int yc0 = min(max(yi, 0), HV - 1), yc1 = min(max(yi + 1, 0), HV - 1);
        float w00 = (vx0 && vy0) ? wx0 * wy0 : 0.0f;
        float w10 = (vx1 && vy0) ? wx1 * wy0 : 0.0f;
        float w01 = (vx0 && vy1) ? wx0 * wy1 : 0.0f;
        float w11 = (vx1 && vy1) ? wx1 * wy1 : 0.0f;
        int ip00 = yc0 * WV + xc0, ip10 = yc0 * WV + xc1;
        int ip01 = yc1 * WV + xc0, ip11 = yc1 * WV + xc1;

        g_ip[t][0] = ip00 * (C_ * 2); g_ip[t][1] = ip10 * (C_ * 2);   // byte offsets
        g_ip[t][2] = ip01 * (C_ * 2); g_ip[t][3] = ip11 * (C_ * 2);
        __half hw0 = __float2half(w00 * at);
        __half hw1 = __float2half(w10 * at);
        __half hw2 = __float2half(w01 * at);
        __half hw3 = __float2half(w11 * at);
        g_wh[t][0] = __halves2half2(hw0, hw0);
        g_wh[t][1] = __halves2half2(hw1, hw1);
        g_wh[t][2] = __halves2half2(hw2, hw2);
        g_wh[t][3] = __halves2half2(hw3, hw3);

        // quad S32 load: slot[ip] = (S[ip], S[ip+1], S[ip+WV], S[ip+WV+1])
        // ip10 in {ip00, ip00+1}; ip01 in {ip00, ip00+WV}; ip11 in {ip01, ip01+1}
        const float4* Sb = (const float4*)S32Q + (size_t)b * NPIX * HEADS;
        float4 sq = Sb[ip00 * HEADS + h];
        float s10 = (ip10 == ip00) ? sq.x : sq.y;
        float s01 = (ip01 == ip00) ? sq.x : sq.z;
        float hi0 = (ip01 == ip00) ? sq.y : sq.w;
        float s11 = (ip11 == ip01) ? s01 : hi0;
        float samp = w00 * sq.x + w10 * s10 + w01 * s01 + w11 * s11;
        float contrib = at * samp;
        #pragma unroll
        for (int s2 = 16; s2; s2 >>= 1) contrib += __shfl_down(contrib, s2, 32);
        if (r == 0) logits_sh[v] = contrib;
    }
    __syncthreads();                                   // barrier 1 (A -> B)

    // ---- lanes 0..7 (f32): argmax + gap test + softmax weights
    if (t < 8) {
        float m = logits_sh[0]; int am = 0;
        #pragma unroll
        for (int v2 = 1; v2 < NV; ++v2) {
            float lv = logits_sh[v2];
            if (lv > m) { m = lv; am = v2; }
        }
        float e = expf(logits_sh[t] - m);
        float ssum = e;
        ssum += __shfl_xor(ssum, 1, 8);
        ssum += __shfl_xor(ssum, 2, 8);
        ssum += __shfl_xor(ssum, 4, 8);
        wf_sh[t] = e / ssum;
        if (t == 0) {
            amax_out[row] = (float)am;
            float m2 = -1e30f;
            #pragma unroll
            for (int v2 = 0; v2 < NV; ++v2) {
                float lv = logits_sh[v2];
                if (v2 != am && lv > m2) m2 = lv;
            }
            float thr = 1e-4f * fmaxf(1.0f, fabsf(m));
            if ((m - m2) < thr) {
                int idx = atomicAdd(cnt, 1);
                list[idx] = row;
            }
        }
    }

    // ---- phase B: 8 groups x 32 threads; group g = v; 8 channels/thread; packed f16 FMA
    {
        int g = t >> 5, lt = t & 31;
        int c0 = lt * 8;
        int c2 = c0 * 2;               // channel byte offset
        int hb = lt >> 2;
        const char* vb = (const char*)(VW + (size_t)b * NPIX * C_);
        __half2 h01 = __float2half2_rn(0.f);
        __half2 h23 = h01, h45 = h01, h67 = h01;
        #pragma unroll
        for (int pp = 0; pp < 2; ++pp) {
            int e0 = g * 32 + hb * 4 + pp * 2;         // entry (v=g, h=hb, p=pp*2); +1 -> p+1
            const int4   ipA = *reinterpret_cast<const int4*>(g_ip[e0]);
            const uint4  whA = *reinterpret_cast<const uint4*>(g_wh[e0]);
            const int4   ipB = *reinterpret_cast<const int4*>(g_ip[e0 + 1]);
            const uint4  whB = *reinterpret_cast<const uint4*>(g_wh[e0 + 1]);
            const uint4 uA0 = *reinterpret_cast<const uint4*>(vb + (ipA.x + c2));
            const uint4 uA1 = *reinterpret_cast<const uint4*>(vb + (ipA.y + c2));
            const uint4 uA2 = *reinterpret_cast<const uint4*>(vb + (ipA.z + c2));
            const uint4 uA3 = *reinterpret_cast<const uint4*>(vb + (ipA.w + c2));
            const uint4 uB0 = *reinterpret_cast<const uint4*>(vb + (ipB.x + c2));
            const uint4 uB1 = *reinterpret_cast<const uint4*>(vb + (ipB.y + c2));
            const uint4 uB2 = *reinterpret_cast<const uint4*>(vb + (ipB.z + c2));
            const uint4 uB3 = *reinterpret_cast<const uint4*>(vb + (ipB.w + c2));
            #define CORNER(WHU, U) { \
                const __half2 wh = *reinterpret_cast<const __half2*>(&WHU); \
                h01 = __hfma2(wh, *reinterpret_cast<const __half2*>(&U.x), h01); \
                h23 = __hfma2(wh, *reinterpret_cast<const __half2*>(&U.y), h23); \
                h45 = __hfma2(wh, *reinterpret_cast<const __half2*>(&U.z), h45); \
                h67 = __hfma2(wh, *reinterpret_cast<const __half2*>(&U.w), h67); }
            CORNER(whA.x, uA0)
            CORNER(whA.y, uA1)
            CORNER(whA.z, uA2)
            CORNER(whA.w, uA3)
            CORNER(whB.x, uB0)
            CORNER(whB.y, uB1)
            CORNER(whB.z, uB2)
            CORNER(whB.w, uB3)
            #undef CORNER
        }
        float a0 = __low2float(h01), a1 = __high2float(h01);
        float a2 = __low2float(h23), a3 = __high2float(h23);
        float a4 = __low2float(h45), a5 = __high2float(h45);
        float a6 = __low2float(h67), a7 = __high2float(h67);
        float4 s0v = {a0, a1, a2, a3}, s1v = {a4, a5, a6, a7};
        *reinterpret_cast<float4*>(&red[g][c0])     = s0v;
        *reinterpret_cast<float4*>(&red[g][c0 + 4]) = s1v;
    }
    __syncthreads();                                   // barrier 2 (B -> epilogue)
    float O = 0.f;
    #pragma unroll
    for (int g8 = 0; g8 < NV; ++g8) O = fmaf(wf_sh[g8], red[g8][t], O);
    out[(size_t)row * C_ + t] = O + b_pre + 2.0f * q_pre;
}

// ---------------- exact replication (compacted: grid-stride over flagged list) ----------------
__global__ void __launch_bounds__(256) exact_kernel(
        const float* __restrict__ v2d, const float* __restrict__ offn,
        const float* __restrict__ attn, const float* __restrict__ grd_col,
        const float* __restrict__ grd_row, const float* __restrict__ Wout,
        const float* __restrict__ bout, const float* __restrict__ Wp,
        const float* __restrict__ bp, const float* __restrict__ query,
        const int* __restrict__ cnt, const int* __restrict__ list,
        float* __restrict__ amax_out) {
#pragma clang fp contract(off)
    int n = *cnt;
    int t = threadIdx.x;
    int h = t >> 5;
    __shared__ float s_off[64];
    __shared__ float s_attn[32];
    __shared__ float wp_lds[C_];
    __shared__ float out_l[NV][C_ + 1];
    __shared__ float bevs_l[NV][C_ + 1];
    __shared__ float lgs[NV];
    wp_lds[t] = Wp[t];

    for (int i = blockIdx.x; i < n; i += gridDim.x) {
        int row = list[i];
        int b = row >> 12;
        int q = row & (NQ - 1);
        if (t < 64)      s_off[t]       = offn[(size_t)row * 64 + t];
        else if (t < 96) s_attn[t - 64] = attn[(size_t)row * 32 + (t - 64)];
        __syncthreads();

        const float* vb = v2d + (size_t)b * NPIX * C_;
        #pragma unroll
        for (int v = 0; v < NV; ++v) {
            float refx = grd_col[q * NV + v];
            float refy = grd_row[q * NV + v];
            float acc = 0.0f;
            #pragma unroll
            for (int p = 0; p < PTS; ++p) {
                float lx = refx + s_off[h * 8 + p * 2 + 0];
                float ly = refy + s_off[h * 8 + p * 2 + 1];
                float x = lx * 46.0f - 0.5f;
                float y = ly * 23.0f - 0.5f;
                float x0f = floorf(x), y0f = floorf(y);
                float wx1 = x - x0f, wy1 = y - y0f;
                float wx0 = 1.0f - wx1, wy0 = 1.0f - wy1;
                int xi = (int)x0f, yi = (int)y0f;
                bool vx0 = (x0f >= 0.0f) && (x0f < 46.0f);
                bool vx1 = (x0f + 1.0f >= 0.0f) && (x0f + 1.0f < 46.0f);
                bool vy0 = (y0f >= 0.0f) && (y0f < 23.0f);
                bool vy1 = (y0f + 1.0f >= 0.0f) && (y0f + 1.0f < 23.0f);
                int xc0 = min(max(xi, 0), WV - 1), xc1 = min(max(xi + 1, 0), WV - 1);
                int yc0 = min(max(yi, 0), HV - 1), yc1 = min(max(yi + 1, 0), HV - 1);
                float g00 = (vx0 && vy0) ? vb[(yc0 * WV + xc0) * C_ + t] : 0.0f;
                float g10 = (vx1 && vy0) ? vb[(yc0 * WV + xc1) * C_ + t] : 0.0f;
                float g01 = (vx0 && vy1) ? vb[(yc1 * WV + xc0) * C_ + t] : 0.0f;
                float g11 = (vx1 && vy1) ? vb[(yc1 * WV + xc1) * C_ + t] : 0.0f;
                float t00 = g00 * (wx0 * wy0);
                float t10 = g10 * (wx1 * wy0);
                float t01 = g01 * (wx0 * wy1);
                float t11 = g11 * (wx1 * wy1);
                float samp = ((t00 + t10) + t01) + t11;
                float pr = s_attn[h * 4 + p] * samp;
                acc = acc + pr;
            }
            out_l[v][t] = acc;
        }
        __syncthreads();

        float bacc[NV];
        #pragma unroll
        for (int v = 0; v < NV; ++v) bacc[v] = 0.f;
        for (int i2 = 0; i2 < C_; ++i2) {
            float w_it = Wout[i2 * C_ + t];
            #pragma unroll
            for (int v = 0; v < NV; ++v) bacc[v] = __builtin_fmaf(out_l[v][i2], w_it, bacc[v]);
        }
        float bo_t = bout[t];
        float qv = query[(size_t)row * C_ + t];
        #pragma unroll
        for (int v = 0; v < NV; ++v) bevs_l[v][t] = (bacc[v] + bo_t) + qv;
        __syncthreads();

        if (t < NV) {
            float lv = 0.f;
            for (int c = 0; c < C_; ++c) lv = __builtin_fmaf(bevs_l[t][c], wp_lds[c], lv);
            lgs[t] = lv + bp[0];
        }
        __syncthreads();

        if (t == 0) {
            float l[NV];
            #pragma unroll
            for (int v = 0; v < NV; ++v) l[v] = lgs[v];
            float m = l[0];
            #pragma unroll
            for (int v = 1; v < NV; ++v) m = fmaxf(m, l[v]);
            float e[NV];
            #pragma unroll
            for (int v = 0; v < NV; ++v) e[v] = expf(l[v] - m);
            float s = ((e[0] + e[1]) + (e[2] + e[3])) + ((e[4] + e[5]) + (e[6] + e[7]));
            float w[NV];
            #pragma unroll
            for (int v = 0; v < NV; ++v) w[v] = e[v] / s;
            int am = 0; float wm = w[0];
            #pragma unroll
            for (int v = 1; v < NV; ++v) { if (w[v] > wm) { wm = w[v]; am = v; } }
            amax_out[row] = (float)am;
        }
        __syncthreads();
    }
}

extern "C" void kernel_launch(void* const* d_in, const int* in_sizes, int n_in,
                              void* d_out, int out_size, void* d_ws, size_t ws_size,
                              hipStream_t stream) {
    const float* query   = (const float*)d_in[0];
    const float* value   = (const float*)d_in[1];
    const float* grd_col = (const float*)d_in[2];
    const float* grd_row = (const float*)d_in[3];
    const float* Wv      = (const float*)d_in[4];
    const float* bv      = (const float*)d_in[5];
    const float* Wo      = (const float*)d_in[6];
    const float* bo      = (const float*)d_in[7];
    const float* Wa      = (const float*)d_in[8];
    const float* ba      = (const float*)d_in[9];
    const float* Wout    = (const float*)d_in[10];
    const float* bout    = (const float*)d_in[11];
    const float* Wp      = (const float*)d_in[12];
    const float* bp      = (const float*)d_in[13];

    float* out  = (float*)d_out;
    float* ws   = (float*)d_ws;
    float* offn = ws;                                        // 32768*64 f32
    float* attn = offn + (size_t)NROW * 64;                  // 32768*32 f32
    float* v2d  = attn + (size_t)NROW * 32;                  // 8464*256 f32
    float* wp2f = v2d + (size_t)BS * NPIX * C_;              // 256 f32
    float* S32Q = wp2f + C_;                                 // 8464*8 float4 = 270848 f32
    int* cnt    = (int*)(S32Q + (size_t)BS * NPIX * HEADS * 4); // 1 int (padded to 4)
    int* list   = cnt + 4;                                   // 32768 int
    ushort_t* VW = (ushort_t*)(list + NROW);                 // 8464*256 fp16
    float* WvWout = (float*)(VW + (size_t)BS * NPIX * C_);   // 256*256 f32
    float* bvW    = WvWout + C_ * C_;                        // 256 f32
    float* amax = out + (size_t)NROW * C_;

    prep_kernel<<<65, 256, 0, stream>>>(Wout, Wp, Wv, bv, WvWout, wp2f, bvW, cnt);
    proj_kernel<<<NVBLK2 + NQBLK, 256, 0, stream>>>(value, Wv, bv, WvWout, bvW, wp2f,
                                                    query, Wo, bo, Wa, ba,
                                                    v2d, VW, S32Q, offn, attn);
    fused_kernel<<<NROW, 256, 0, stream>>>(VW, offn, attn, grd_col, grd_row, S32Q,
                                           query, bout, out, amax, cnt, list);
    exact_kernel<<<512, 256, 0, stream>>>(v2d, offn, attn, grd_col, grd_row,
                                          Wout, bout, Wp, bp, query, cnt, list, amax);
}

// Round 12
// 212.840 us; speedup vs baseline: 1.1341x; 1.0320x over previous
//
#include <hip/hip_runtime.h>
#include <hip/hip_fp16.h>

#define NV 8
#define NQ 4096
#define C_ 256
#define HEADS 8
#define PTS 4
#define HV 23
#define WV 46
#define NPIX (HV*WV)       // 1058
#define BS 8
#define NROW (BS*NQ)       // 32768
#define NVBLK2 ((BS*NPIX)/16) // 529 value blocks (16 rows each)
#define NQBLK (NROW/16)       // 2048 query blocks

typedef unsigned short ushort_t;
typedef unsigned int uint_t;

// ---------------- prep (65 blocks): 0..63 WvWout = Wv@Wout; 64: wp2f = Wout@Wp, bvW = bv@Wout, cnt=0 ----------------
__global__ void prep_kernel(const float* __restrict__ Wout, const float* __restrict__ Wp,
                            const float* __restrict__ Wv, const float* __restrict__ bv,
                            float* __restrict__ WvWout, float* __restrict__ wp2f,
                            float* __restrict__ bvW, int* __restrict__ cnt) {
    int blk = blockIdx.x;
    int t = threadIdx.x;
    __shared__ float rows[4][C_];
    if (blk < 64) {
        int r0 = blk * 4;
        #pragma unroll
        for (int r = 0; r < 4; ++r) rows[r][t] = Wv[(r0 + r) * C_ + t];
        __syncthreads();
        float acc[4] = {0.f, 0.f, 0.f, 0.f};
        for (int k = 0; k < C_; ++k) {
            float w = Wout[k * C_ + t];
            acc[0] = fmaf(rows[0][k], w, acc[0]);
            acc[1] = fmaf(rows[1][k], w, acc[1]);
            acc[2] = fmaf(rows[2][k], w, acc[2]);
            acc[3] = fmaf(rows[3][k], w, acc[3]);
        }
        #pragma unroll
        for (int r = 0; r < 4; ++r) WvWout[(r0 + r) * C_ + t] = acc[r];
    } else {
        if (t == 0) *cnt = 0;
        float a = 0.f;
        for (int c = 0; c < C_; ++c) a = fmaf(Wout[t * C_ + c], Wp[c], a);
        wp2f[t] = a;
        float fb = 0.f;
        for (int d = 0; d < C_; ++d) fb = fmaf(bv[d], Wout[d * C_ + t], fb);
        bvW[t] = fb;
    }
}

// ---------------- proj: value blocks (16 rows, one k-loop: v2d exact + VW) + quad S32Q; query blocks ----------------
// Query part Wa waves now lane-split: lanes 0-31 rows 0-3, lanes 32-63 rows 4-7 (4 accs each,
// full lane utilization; same per-(row,col) sequential-k chains -> attn bit-identical).
__global__ void proj_kernel(const float* __restrict__ value, const float* __restrict__ Wv,
                            const float* __restrict__ bv, const float* __restrict__ WvWout,
                            const float* __restrict__ bvW, const float* __restrict__ wp2f,
                            const float* __restrict__ query,
                            const float* __restrict__ Wo, const float* __restrict__ bo,
                            const float* __restrict__ Wa, const float* __restrict__ ba,
                            float* __restrict__ v2d, ushort_t* __restrict__ VW,
                            float* __restrict__ S32Q, float* __restrict__ offn,
                            float* __restrict__ attn) {
#pragma clang fp contract(off)
    __shared__ float sbuf[16 * C_ + 16 * 32];
    int blk = blockIdx.x;
    int t = threadIdx.x;
    if (blk < NVBLK2) {
        // ===== value part: 16 rows/block, single k-loop, 32 accumulator chains =====
        float (*rows)[C_] = (float (*)[C_])sbuf;             // [16][256] value rows
        int r0 = blk * 16;
        #pragma unroll
        for (int i = 0; i < 16; ++i) {
            int idx = t + i * 256;
            rows[idx >> 8][idx & 255] = value[(size_t)r0 * C_ + idx];
        }
        __syncthreads();
        float acc[16], accW[16];
        #pragma unroll
        for (int r = 0; r < 16; ++r) { acc[r] = 0.f; accW[r] = 0.f; }
        for (int k4 = 0; k4 < C_ / 4; ++k4) {
            int k = k4 * 4;
            float w0 = Wv[(k + 0) * C_ + t], w1 = Wv[(k + 1) * C_ + t];
            float w2 = Wv[(k + 2) * C_ + t], w3 = Wv[(k + 3) * C_ + t];
            float u0 = WvWout[(k + 0) * C_ + t], u1 = WvWout[(k + 1) * C_ + t];
            float u2 = WvWout[(k + 2) * C_ + t], u3 = WvWout[(k + 3) * C_ + t];
            #pragma unroll
            for (int r = 0; r < 16; ++r) {
                const float4 qv = *(reinterpret_cast<const float4*>(rows[r]) + k4);
                acc[r] = __builtin_fmaf(qv.x, w0, acc[r]);   // exact: sequential k order
                acc[r] = __builtin_fmaf(qv.y, w1, acc[r]);
                acc[r] = __builtin_fmaf(qv.z, w2, acc[r]);
                acc[r] = __builtin_fmaf(qv.w, w3, acc[r]);
                accW[r] = fmaf(qv.x, u0, accW[r]);
                accW[r] = fmaf(qv.y, u1, accW[r]);
                accW[r] = fmaf(qv.z, u2, accW[r]);
                accW[r] = fmaf(qv.w, u3, accW[r]);
            }
        }
        float b = bv[t];
        float b2 = bvW[t];
        #pragma unroll
        for (int r = 0; r < 16; ++r) {
            acc[r] = acc[r] + b;   // vd
            v2d[(size_t)(r0 + r) * C_ + t] = acc[r];
            VW[(size_t)(r0 + r) * C_ + t] = __half_as_ushort(__float2half(accW[r] + b2));
        }
        // S32Q scatter: each S[row] lands at slot[row].x, slot[row-1].y, slot[row-WV].z, slot[row-WV-1].w
        float wpt = wp2f[t];
        #pragma unroll
        for (int r = 0; r < 16; ++r) {
            float p = acc[r] * wpt;
            p += __shfl_down(p, 16, 32);
            p += __shfl_down(p, 8, 32);
            p += __shfl_down(p, 4, 32);
            p += __shfl_down(p, 2, 32);
            p += __shfl_down(p, 1, 32);
            if ((t & 31) == 0) {
                int row = r0 + r;
                int h = t >> 5;
                int pix = row - (row / NPIX) * NPIX;
                S32Q[((size_t)row * HEADS + h) * 4 + 0] = p;
                if (pix >= 1)
                    S32Q[((size_t)(row - 1) * HEADS + h) * 4 + 1] = p;
                if (pix >= WV)
                    S32Q[((size_t)(row - WV) * HEADS + h) * 4 + 2] = p;
                if (pix >= WV + 1)
                    S32Q[((size_t)(row - WV - 1) * HEADS + h) * 4 + 3] = p;
            }
        }
    } else {
        // ===== query part: 16 rows/block, two independent 128-thread halves, float4 LDS =====
        int qb = blk - NVBLK2;
        int half = t >> 7, tt = t & 127;
        int rb = qb * 16 + half * 8;
        float (*qs)[C_] = (float (*)[C_])sbuf;
        float (*lg)[32] = (float (*)[32])(sbuf + 16 * C_);
        #pragma unroll
        for (int i = 0; i < 16; ++i) {
            int idx = tt + i * 128;
            int rr = idx >> 8, cc = idx & 255;
            qs[half * 8 + rr][cc] = query[(size_t)(rb + rr) * C_ + cc];
        }
        __syncthreads();
        if (tt < 64) {
            float acc[8] = {0.f, 0.f, 0.f, 0.f, 0.f, 0.f, 0.f, 0.f};
            for (int k4 = 0; k4 < C_ / 4; ++k4) {
                int k = k4 * 4;
                float w0 = Wo[(k + 0) * 64 + tt], w1 = Wo[(k + 1) * 64 + tt];
                float w2 = Wo[(k + 2) * 64 + tt], w3 = Wo[(k + 3) * 64 + tt];
                #pragma unroll
                for (int r = 0; r < 8; ++r) {
                    const float4 qv = *(reinterpret_cast<const float4*>(qs[half * 8 + r]) + k4);
                    acc[r] = __builtin_fmaf(qv.x, w0, acc[r]);
                    acc[r] = __builtin_fmaf(qv.y, w1, acc[r]);
                    acc[r] = __builtin_fmaf(qv.z, w2, acc[r]);
                    acc[r] = __builtin_fmaf(qv.w, w3, acc[r]);
                }
            }
            float b = bo[tt];
            float nrm = (tt & 1) ? 23.0f : 46.0f;
            #pragma unroll
            for (int r = 0; r < 8; ++r) offn[(size_t)(rb + r) * 64 + tt] = (acc[r] + b) / nrm;
        } else {
            // Wa wave, lane-split: u=tt-64 in 0..63; j = u&31 (cols, upper lanes broadcast same);
            // rbase = (u>>5)*4 -> lanes 0-31 rows 0-3, lanes 32-63 rows 4-7. 4 accs, all lanes busy.
            int u = tt - 64;
            int j = u & 31;
            int rbase = (u >> 5) * 4;
            float acc[4] = {0.f, 0.f, 0.f, 0.f};
            for (int k4 = 0; k4 < C_ / 4; ++k4) {
                int k = k4 * 4;
                float w0 = Wa[(k + 0) * 32 + j], w1 = Wa[(k + 1) * 32 + j];
                float w2 = Wa[(k + 2) * 32 + j], w3 = Wa[(k + 3) * 32 + j];
                #pragma unroll
                for (int r = 0; r < 4; ++r) {
                    const float4 qv = *(reinterpret_cast<const float4*>(qs[half * 8 + rbase + r]) + k4);
                    acc[r] = __builtin_fmaf(qv.x, w0, acc[r]);
                    acc[r] = __builtin_fmaf(qv.y, w1, acc[r]);
                    acc[r] = __builtin_fmaf(qv.z, w2, acc[r]);
                    acc[r] = __builtin_fmaf(qv.w, w3, acc[r]);
                }
            }
            float b = ba[j];
            #pragma unroll
            for (int r = 0; r < 4; ++r) lg[half * 8 + rbase + r][j] = acc[r] + b;
        }
        __syncthreads();
        if (tt < 64) {
            int r = tt >> 3, h = tt & 7;
            int lr = half * 8 + r;
            float v0 = lg[lr][h * 4 + 0], v1 = lg[lr][h * 4 + 1];
            float v2 = lg[lr][h * 4 + 2], v3 = lg[lr][h * 4 + 3];
            float m = fmaxf(fmaxf(fmaxf(v0, v1), v2), v3);
            float e0 = expf(v0 - m), e1 = expf(v1 - m), e2 = expf(v2 - m), e3 = expf(v3 - m);
            float s = ((e0 + e1) + e2) + e3;
            attn[(size_t)(rb + r) * 32 + h * 4 + 0] = e0 / s;
            attn[(size_t)(rb + r) * 32 + h * 4 + 1] = e1 / s;
            attn[(size_t)(rb + r) * 32 + h * 4 + 2] = e2 / s;
            attn[(size_t)(rb + r) * 32 + h * 4 + 3] = e3 / s;
        }
    }
}

// ---------------- fused: f32 gap-tested logits (quad S32Q, 1x16B load) + hfma2 sampling + epilogue prefetch ----------------
__global__ void __launch_bounds__(256) fused_kernel(
        const ushort_t* __restrict__ VW, const float* __restrict__ offn,
        const float* __restrict__ attn, const float* __restrict__ grd_col,
        const float* __restrict__ grd_row, const float* __restrict__ S32Q,
        const float* __restrict__ query, const float* __restrict__ bout,
        float* __restrict__ out, float* __restrict__ amax_out,
        int* __restrict__ cnt, int* __restrict__ list) {
    int bid = blockIdx.x;
    int row = ((bid & 7) << 12) | (bid >> 3);   // XCD-bijective: batch <-> XCD affinity
    int b = row >> 12;
    int q = row & (NQ - 1);
    int t = threadIdx.x;
    __shared__ __align__(16) int     g_ip[256][4];
    __shared__ __align__(16) __half2 g_wh[256][4];   // duplicated half2 per corner weight
    __shared__ __align__(16) float red[NV][C_];
    __shared__ float logits_sh[NV];
    __shared__ float wf_sh[NV];

    // epilogue prefetch: issue early so L2/HBM latency hides under phases A/B
    float q_pre = query[(size_t)row * C_ + t];
    float b_pre = bout[t];

    // ---- phase A (f32): t = v*32 + (h*4+p)
    {
        int v = t >> 5, r = t & 31, h = r >> 2;
        const float2 off2 = ((const float2*)(offn + (size_t)row * 64))[r];
        float at = attn[(size_t)row * 32 + r];
        float refx = grd_col[q * NV + v];
        float refy = grd_row[q * NV + v];
        float lx = refx + off2.x;
        float ly = refy + off2.y;
        float x = lx * 46.0f - 0.5f;
        float y = ly * 23.0f - 0.5f;
        float x0f = floorf(x), y0f = floorf(y);
        float wx1 = x - x0f, wy1 = y - y0f;
        float wx0 = 1.0f - wx1, wy0 = 1.0f - wy1;
        int xi = (int)x0f, yi = (int)y0f;
        bool vx0 = (x0f >= 0.0f) && (x0f < 46.0f);
        bool vx1 = (x0f + 1.0f >= 0.0f) && (x0f + 1.0f < 46.0f);
        bool vy0 = (y0f >= 0.0f) && (y0f < 23.0f);
        bool vy1 = (y0f + 1.0f >= 0.0f) && (y0f + 1.0f < 23.0f);
        int xc0 = min(max(xi, 0), WV - 1), xc1 = min(max(xi + 1, 0), WV - 1);
        int yc0 = min(max(yi, 0), HV - 1), yc1 = min(max(yi + 1, 0), HV - 1);
        float w00 = (vx0 && vy0) ? wx0 * wy0 : 0.0f;
        float w10 = (vx1 && vy0) ? wx1 * wy0 : 0.0f;
        float w01 = (vx0 && vy1) ? wx0 * wy1 : 0.0f;
        float w11 = (vx1 && vy1) ? wx1 * wy1 : 0.0f;
        int ip00 = yc0 * WV + xc0, ip10 = yc0 * WV + xc1;
        int ip01 = yc1 * WV + xc0, ip11 = yc1 * WV + xc1;

        g_ip[t][0] = ip00 * (C_ * 2); g_ip[t][1] = ip10 * (C_ * 2);   // byte offsets
        g_ip[t][2] = ip01 * (C_ * 2); g_ip[t][3] = ip11 * (C_ * 2);
        __half hw0 = __float2half(w00 * at);
        __half hw1 = __float2half(w10 * at);
        __half hw2 = __float2half(w01 * at);
        __half hw3 = __float2half(w11 * at);
        g_wh[t][0] = __halves2half2(hw0, hw0);
        g_wh[t][1] = __halves2half2(hw1, hw1);
        g_wh[t][2] = __halves2half2(hw2, hw2);
        g_wh[t][3] = __halves2half2(hw3, hw3);

        // quad S32 load: slot[ip] = (S[ip], S[ip+1], S[ip+WV], S[ip+WV+1])
        const float4* Sb = (const float4*)S32Q + (size_t)b * NPIX * HEADS;
        float4 sq = Sb[ip00 * HEADS + h];
        float s10 = (ip10 == ip00) ? sq.x : sq.y;
        float s01 = (ip01 == ip00) ? sq.x : sq.z;
        float hi0 = (ip01 == ip00) ? sq.y : sq.w;
        float s11 = (ip11 == ip01) ? s01 : hi0;
        float samp = w00 * sq.x + w10 * s10 + w01 * s01 + w11 * s11;
        float contrib = at * samp;
        #pragma unroll
        for (int s2 = 16; s2; s2 >>= 1) contrib += __shfl_down(contrib, s2, 32);
        if (r == 0) logits_sh[v] = contrib;
    }
    __syncthreads();                                   // barrier 1 (A -> B)

    // ---- lanes 0..7 (f32): argmax + gap test + softmax weights
    if (t < 8) {
        float m = logits_sh[0]; int am = 0;
        #pragma unroll
        for (int v2 = 1; v2 < NV; ++v2) {
            float lv = logits_sh[v2];
            if (lv > m) { m = lv; am = v2; }
        }
        float e = expf(logits_sh[t] - m);
        float ssum = e;
        ssum += __shfl_xor(ssum, 1, 8);
        ssum += __shfl_xor(ssum, 2, 8);
        ssum += __shfl_xor(ssum, 4, 8);
        wf_sh[t] = e / ssum;
        if (t == 0) {
            amax_out[row] = (float)am;
            float m2 = -1e30f;
            #pragma unroll
            for (int v2 = 0; v2 < NV; ++v2) {
                float lv = logits_sh[v2];
                if (v2 != am && lv > m2) m2 = lv;
            }
            float thr = 1e-4f * fmaxf(1.0f, fabsf(m));
            if ((m - m2) < thr) {
                int idx = atomicAdd(cnt, 1);
                list[idx] = row;
            }
        }
    }

    // ---- phase B: 8 groups x 32 threads; group g = v; 8 channels/thread; packed f16 FMA
    {
        int g = t >> 5, lt = t & 31;
        int c0 = lt * 8;
        int c2 = c0 * 2;               // channel byte offset
        int hb = lt >> 2;
        const char* vb = (const char*)(VW + (size_t)b * NPIX * C_);
        __half2 h01 = __float2half2_rn(0.f);
        __half2 h23 = h01, h45 = h01, h67 = h01;
        #pragma unroll
        for (int pp = 0; pp < 2; ++pp) {
            int e0 = g * 32 + hb * 4 + pp * 2;         // entry (v=g, h=hb, p=pp*2); +1 -> p+1
            const int4   ipA = *reinterpret_cast<const int4*>(g_ip[e0]);
            const uint4  whA = *reinterpret_cast<const uint4*>(g_wh[e0]);
            const int4   ipB = *reinterpret_cast<const int4*>(g_ip[e0 + 1]);
            const uint4  whB = *reinterpret_cast<const uint4*>(g_wh[e0 + 1]);
            const uint4 uA0 = *reinterpret_cast<const uint4*>(vb + (ipA.x + c2));
            const uint4 uA1 = *reinterpret_cast<const uint4*>(vb + (ipA.y + c2));
            const uint4 uA2 = *reinterpret_cast<const uint4*>(vb + (ipA.z + c2));
            const uint4 uA3 = *reinterpret_cast<const uint4*>(vb + (ipA.w + c2));
            const uint4 uB0 = *reinterpret_cast<const uint4*>(vb + (ipB.x + c2));
            const uint4 uB1 = *reinterpret_cast<const uint4*>(vb + (ipB.y + c2));
            const uint4 uB2 = *reinterpret_cast<const uint4*>(vb + (ipB.z + c2));
            const uint4 uB3 = *reinterpret_cast<const uint4*>(vb + (ipB.w + c2));
            #define CORNER(WHU, U) { \
                const __half2 wh = *reinterpret_cast<const __half2*>(&WHU); \
                h01 = __hfma2(wh, *reinterpret_cast<const __half2*>(&U.x), h01); \
                h23 = __hfma2(wh, *reinterpret_cast<const __half2*>(&U.y), h23); \
                h45 = __hfma2(wh, *reinterpret_cast<const __half2*>(&U.z), h45); \
                h67 = __hfma2(wh, *reinterpret_cast<const __half2*>(&U.w), h67); }
            CORNER(whA.x, uA0)
            CORNER(whA.y, uA1)
            CORNER(whA.z, uA2)
            CORNER(whA.w, uA3)
            CORNER(whB.x, uB0)
            CORNER(whB.y, uB1)
            CORNER(whB.z, uB2)
            CORNER(whB.w, uB3)
            #undef CORNER
        }
        float a0 = __low2float(h01), a1 = __high2float(h01);
        float a2 = __low2float(h23), a3 = __high2float(h23);
        float a4 = __low2float(h45), a5 = __high2float(h45);
        float a6 = __low2float(h67), a7 = __high2float(h67);
        float4 s0v = {a0, a1, a2, a3}, s1v = {a4, a5, a6, a7};
        *reinterpret_cast<float4*>(&red[g][c0])     = s0v;
        *reinterpret_cast<float4*>(&red[g][c0 + 4]) = s1v;
    }
    __syncthreads();                                   // barrier 2 (B -> epilogue)
    float O = 0.f;
    #pragma unroll
    for (int g8 = 0; g8 < NV; ++g8) O = fmaf(wf_sh[g8], red[g8][t], O);
    out[(size_t)row * C_ + t] = O + b_pre + 2.0f * q_pre;
}

// ---------------- exact replication (compacted: grid-stride over flagged list) ----------------
__global__ void __launch_bounds__(256) exact_kernel(
        const float* __restrict__ v2d, const float* __restrict__ offn,
        const float* __restrict__ attn, const float* __restrict__ grd_col,
        const float* __restrict__ grd_row, const float* __restrict__ Wout,
        const float* __restrict__ bout, const float* __restrict__ Wp,
        const float* __restrict__ bp, const float* __restrict__ query,
        const int* __restrict__ cnt, const int* __restrict__ list,
        float* __restrict__ amax_out) {
#pragma clang fp contract(off)
    int n = *cnt;
    int t = threadIdx.x;
    int h = t >> 5;
    __shared__ float s_off[64];
    __shared__ float s_attn[32];
    __shared__ float wp_lds[C_];
    __shared__ float out_l[NV][C_ + 1];
    __shared__ float bevs_l[NV][C_ + 1];
    __shared__ float lgs[NV];
    wp_lds[t] = Wp[t];

    for (int i = blockIdx.x; i < n; i += gridDim.x) {
        int row = list[i];
        int b = row >> 12;
        int q = row & (NQ - 1);
        if (t < 64)      s_off[t]       = offn[(size_t)row * 64 + t];
        else if (t < 96) s_attn[t - 64] = attn[(size_t)row * 32 + (t - 64)];
        __syncthreads();

        const float* vb = v2d + (size_t)b * NPIX * C_;
        #pragma unroll
        for (int v = 0; v < NV; ++v) {
            float refx = grd_col[q * NV + v];
            float refy = grd_row[q * NV + v];
            float acc = 0.0f;
            #pragma unroll
            for (int p = 0; p < PTS; ++p) {
                float lx = refx + s_off[h * 8 + p * 2 + 0];
                float ly = refy + s_off[h * 8 + p * 2 + 1];
                float x = lx * 46.0f - 0.5f;
                float y = ly * 23.0f - 0.5f;
                float x0f = floorf(x), y0f = floorf(y);
                float wx1 = x - x0f, wy1 = y - y0f;
                float wx0 = 1.0f - wx1, wy0 = 1.0f - wy1;
                int xi = (int)x0f, yi = (int)y0f;
                bool vx0 = (x0f >= 0.0f) && (x0f < 46.0f);
                bool vx1 = (x0f + 1.0f >= 0.0f) && (x0f + 1.0f < 46.0f);
                bool vy0 = (y0f >= 0.0f) && (y0f < 23.0f);
                bool vy1 = (y0f + 1.0f >= 0.0f) && (y0f + 1.0f < 23.0f);
                int xc0 = min(max(xi, 0), WV - 1), xc1 = min(max(xi + 1, 0), WV - 1);
                int yc0 = min(max(yi, 0), HV - 1), yc1 = min(max(yi + 1, 0), HV - 1);
                float g00 = (vx0 && vy0) ? vb[(yc0 * WV + xc0) * C_ + t] : 0.0f;
                float g10 = (vx1 && vy0) ? vb[(yc0 * WV + xc1) * C_ + t] : 0.0f;
                float g01 = (vx0 && vy1) ? vb[(yc1 * WV + xc0) * C_ + t] : 0.0f;
                float g11 = (vx1 && vy1) ? vb[(yc1 * WV + xc1) * C_ + t] : 0.0f;
                float t00 = g00 * (wx0 * wy0);
                float t10 = g10 * (wx1 * wy0);
                float t01 = g01 * (wx0 * wy1);
                float t11 = g11 * (wx1 * wy1);
                float samp = ((t00 + t10) + t01) + t11;
                float pr = s_attn[h * 4 + p] * samp;
                acc = acc + pr;
            }
            out_l[v][t] = acc;
        }
        __syncthreads();

        float bacc[NV];
        #pragma unroll
        for (int v = 0; v < NV; ++v) bacc[v] = 0.f;
        for (int i2 = 0; i2 < C_; ++i2) {
            float w_it = Wout[i2 * C_ + t];
            #pragma unroll
            for (int v = 0; v < NV; ++v) bacc[v] = __builtin_fmaf(out_l[v][i2], w_it, bacc[v]);
        }
        float bo_t = bout[t];
        float qv = query[(size_t)row * C_ + t];
        #pragma unroll
        for (int v = 0; v < NV; ++v) bevs_l[v][t] = (bacc[v] + bo_t) + qv;
        __syncthreads();

        if (t < NV) {
            float lv = 0.f;
            for (int c = 0; c < C_; ++c) lv = __builtin_fmaf(bevs_l[t][c], wp_lds[c], lv);
            lgs[t] = lv + bp[0];
        }
        __syncthreads();

        if (t == 0) {
            float l[NV];
            #pragma unroll
            for (int v = 0; v < NV; ++v) l[v] = lgs[v];
            float m = l[0];
            #pragma unroll
            for (int v = 1; v < NV; ++v) m = fmaxf(m, l[v]);
            float e[NV];
            #pragma unroll
            for (int v = 0; v < NV; ++v) e[v] = expf(l[v] - m);
            float s = ((e[0] + e[1]) + (e[2] + e[3])) + ((e[4] + e[5]) + (e[6] + e[7]));
            float w[NV];
            #pragma unroll
            for (int v = 0; v < NV; ++v) w[v] = e[v] / s;
            int am = 0; float wm = w[0];
            #pragma unroll
            for (int v = 1; v < NV; ++v) { if (w[v] > wm) { wm = w[v]; am = v; } }
            amax_out[row] = (float)am;
        }
        __syncthreads();
    }
}

extern "C" void kernel_launch(void* const* d_in, const int* in_sizes, int n_in,
                              void* d_out, int out_size, void* d_ws, size_t ws_size,
                              hipStream_t stream) {
    const float* query   = (const float*)d_in[0];
    const float* value   = (const float*)d_in[1];
    const float* grd_col = (const float*)d_in[2];
    const float* grd_row = (const float*)d_in[3];
    const float* Wv      = (const float*)d_in[4];
    const float* bv      = (const float*)d_in[5];
    const float* Wo      = (const float*)d_in[6];
    const float* bo      = (const float*)d_in[7];
    const float* Wa      = (const float*)d_in[8];
    const float* ba      = (const float*)d_in[9];
    const float* Wout    = (const float*)d_in[10];
    const float* bout    = (const float*)d_in[11];
    const float* Wp      = (const float*)d_in[12];
    const float* bp      = (const float*)d_in[13];

    float* out  = (float*)d_out;
    float* ws   = (float*)d_ws;
    float* offn = ws;                                        // 32768*64 f32
    float* attn = offn + (size_t)NROW * 64;                  // 32768*32 f32
    float* v2d  = attn + (size_t)NROW * 32;                  // 8464*256 f32
    float* wp2f = v2d + (size_t)BS * NPIX * C_;              // 256 f32
    float* S32Q = wp2f + C_;                                 // 8464*8 float4 = 270848 f32
    int* cnt    = (int*)(S32Q + (size_t)BS * NPIX * HEADS * 4); // 1 int (padded to 4)
    int* list   = cnt + 4;                                   // 32768 int
    ushort_t* VW = (ushort_t*)(list + NROW);                 // 8464*256 fp16
    float* WvWout = (float*)(VW + (size_t)BS * NPIX * C_);   // 256*256 f32
    float* bvW    = WvWout + C_ * C_;                        // 256 f32
    float* amax = out + (size_t)NROW * C_;

    prep_kernel<<<65, 256, 0, stream>>>(Wout, Wp, Wv, bv, WvWout, wp2f, bvW, cnt);
    proj_kernel<<<NVBLK2 + NQBLK, 256, 0, stream>>>(value, Wv, bv, WvWout, bvW, wp2f,
                                                    query, Wo, bo, Wa, ba,
                                                    v2d, VW, S32Q, offn, attn);
    fused_kernel<<<NROW, 256, 0, stream>>>(VW, offn, attn, grd_col, grd_row, S32Q,
                                           query, bout, out, amax, cnt, list);
    exact_kernel<<<512, 256, 0, stream>>>(v2d, offn, attn, grd_col, grd_row,
                                          Wout, bout, Wp, bp, query, cnt, list, amax);
}

// Round 13
// 208.472 us; speedup vs baseline: 1.1578x; 1.0210x over previous
//
#include <hip/hip_runtime.h>
#include <hip/hip_fp16.h>

#define NV 8
#define NQ 4096
#define C_ 256
#define HEADS 8
#define PTS 4
#define HV 23
#define WV 46
#define NPIX (HV*WV)       // 1058
#define BS 8
#define NROW (BS*NQ)       // 32768
#define NVBLK2 ((BS*NPIX)/16) // 529 value blocks (16 rows each)
#define NQBLK (NROW/16)       // 2048 query blocks

typedef unsigned short ushort_t;
typedef unsigned int uint_t;
typedef float float2v __attribute__((ext_vector_type(2)));

// packed f32 FMA: ACC(pair) += V(pair) * W(pair, both halves equal) -- IEEE-identical per lane
#define PKFMA(ACC, V, W) asm("v_pk_fma_f32 %0, %1, %2, %0" : "+v"(ACC) : "v"(V), "v"(W))

// ---------------- prep (65 blocks): 0..63 WvWout = Wv@Wout; 64: wp2f = Wout@Wp, bvW = bv@Wout, cnt=0 ----------------
__global__ void prep_kernel(const float* __restrict__ Wout, const float* __restrict__ Wp,
                            const float* __restrict__ Wv, const float* __restrict__ bv,
                            float* __restrict__ WvWout, float* __restrict__ wp2f,
                            float* __restrict__ bvW, int* __restrict__ cnt) {
    int blk = blockIdx.x;
    int t = threadIdx.x;
    __shared__ float rows[4][C_];
    if (blk < 64) {
        int r0 = blk * 4;
        #pragma unroll
        for (int r = 0; r < 4; ++r) rows[r][t] = Wv[(r0 + r) * C_ + t];
        __syncthreads();
        float acc[4] = {0.f, 0.f, 0.f, 0.f};
        for (int k = 0; k < C_; ++k) {
            float w = Wout[k * C_ + t];
            acc[0] = fmaf(rows[0][k], w, acc[0]);
            acc[1] = fmaf(rows[1][k], w, acc[1]);
            acc[2] = fmaf(rows[2][k], w, acc[2]);
            acc[3] = fmaf(rows[3][k], w, acc[3]);
        }
        #pragma unroll
        for (int r = 0; r < 4; ++r) WvWout[(r0 + r) * C_ + t] = acc[r];
    } else {
        if (t == 0) *cnt = 0;
        float a = 0.f;
        for (int c = 0; c < C_; ++c) a = fmaf(Wout[t * C_ + c], Wp[c], a);
        wp2f[t] = a;
        float fb = 0.f;
        for (int d = 0; d < C_; ++d) fb = fmaf(bv[d], Wout[d * C_ + t], fb);
        bvW[t] = fb;
    }
}

// ---------------- proj: value blocks (pair-interleaved LDS + v_pk_fma_f32) + quad S32Q; query blocks ----------------
// Value rows stored pair-interleaved: lds[p*512 + k*2 + e] = value[r0+2p+e][k]. One b128 read
// yields {vA[k],vB[k],vA[k+1],vB[k+1]} = two pk operands; 128 scalar FMA/iter -> 64 pk-FMA.
// Per-(row,col) chains keep exact sequential-k order -> v2d/VW/S32Q bit-identical.
__global__ void proj_kernel(const float* __restrict__ value, const float* __restrict__ Wv,
                            const float* __restrict__ bv, const float* __restrict__ WvWout,
                            const float* __restrict__ bvW, const float* __restrict__ wp2f,
                            const float* __restrict__ query,
                            const float* __restrict__ Wo, const float* __restrict__ bo,
                            const float* __restrict__ Wa, const float* __restrict__ ba,
                            float* __restrict__ v2d, ushort_t* __restrict__ VW,
                            float* __restrict__ S32Q, float* __restrict__ offn,
                            float* __restrict__ attn) {
#pragma clang fp contract(off)
    __shared__ __align__(16) float sbuf[16 * C_ + 16 * 32];
    int blk = blockIdx.x;
    int t = threadIdx.x;
    if (blk < NVBLK2) {
        // ===== value part =====
        int r0 = blk * 16;
        #pragma unroll
        for (int i = 0; i < 16; ++i) {
            int idx = t + i * 256;
            int row = idx >> 8, col = idx & 255;
            sbuf[((row >> 1) << 9) + (col << 1) + (row & 1)] = value[(size_t)r0 * C_ + idx];
        }
        __syncthreads();
        float2v acc2[8], accW2[8];
        #pragma unroll
        for (int p = 0; p < 8; ++p) { acc2[p] = (float2v){0.f, 0.f}; accW2[p] = (float2v){0.f, 0.f}; }
        const float4* ldsq = (const float4*)sbuf;
        for (int k4 = 0; k4 < C_ / 4; ++k4) {
            int k = k4 * 4;
            float w0 = Wv[(k + 0) * C_ + t], w1 = Wv[(k + 1) * C_ + t];
            float w2 = Wv[(k + 2) * C_ + t], w3 = Wv[(k + 3) * C_ + t];
            float u0 = WvWout[(k + 0) * C_ + t], u1 = WvWout[(k + 1) * C_ + t];
            float u2 = WvWout[(k + 2) * C_ + t], u3 = WvWout[(k + 3) * C_ + t];
            float2v w20 = {w0, w0}, w21 = {w1, w1}, w22 = {w2, w2}, w23 = {w3, w3};
            float2v u20 = {u0, u0}, u21 = {u1, u1}, u22 = {u2, u2}, u23 = {u3, u3};
            #pragma unroll
            for (int p = 0; p < 8; ++p) {
                const float4 qa = ldsq[p * 128 + 2 * k4];       // {vA[k],vB[k],vA[k+1],vB[k+1]}
                const float4 qb = ldsq[p * 128 + 2 * k4 + 1];   // k+2, k+3
                float2v v0 = {qa.x, qa.y}, v1 = {qa.z, qa.w};
                float2v v2 = {qb.x, qb.y}, v3 = {qb.z, qb.w};
                PKFMA(acc2[p], v0, w20);    // exact: sequential k order per row chain
                PKFMA(acc2[p], v1, w21);
                PKFMA(acc2[p], v2, w22);
                PKFMA(acc2[p], v3, w23);
                PKFMA(accW2[p], v0, u20);
                PKFMA(accW2[p], v1, u21);
                PKFMA(accW2[p], v2, u22);
                PKFMA(accW2[p], v3, u23);
            }
        }
        float b = bv[t];
        float b2 = bvW[t];
        float wpt = wp2f[t];
        #pragma unroll
        for (int r = 0; r < 16; ++r) {
            float a  = (r & 1) ? acc2[r >> 1].y  : acc2[r >> 1].x;
            float aw = (r & 1) ? accW2[r >> 1].y : accW2[r >> 1].x;
            float vd = a + b;
            v2d[(size_t)(r0 + r) * C_ + t] = vd;
            VW[(size_t)(r0 + r) * C_ + t] = __half_as_ushort(__float2half(aw + b2));
            // S32Q scatter (same as R12): slot[row].x, slot[row-1].y, slot[row-WV].z, slot[row-WV-1].w
            float p = vd * wpt;
            p += __shfl_down(p, 16, 32);
            p += __shfl_down(p, 8, 32);
            p += __shfl_down(p, 4, 32);
            p += __shfl_down(p, 2, 32);
            p += __shfl_down(p, 1, 32);
            if ((t & 31) == 0) {
                int row = r0 + r;
                int h = t >> 5;
                int pix = row - (row / NPIX) * NPIX;
                S32Q[((size_t)row * HEADS + h) * 4 + 0] = p;
                if (pix >= 1)
                    S32Q[((size_t)(row - 1) * HEADS + h) * 4 + 1] = p;
                if (pix >= WV)
                    S32Q[((size_t)(row - WV) * HEADS + h) * 4 + 2] = p;
                if (pix >= WV + 1)
                    S32Q[((size_t)(row - WV - 1) * HEADS + h) * 4 + 3] = p;
            }
        }
    } else {
        // ===== query part: 16 rows/block, two independent 128-thread halves (R12-verified) =====
        int qb = blk - NVBLK2;
        int half = t >> 7, tt = t & 127;
        int rb = qb * 16 + half * 8;
        float (*qs)[C_] = (float (*)[C_])sbuf;
        float (*lg)[32] = (float (*)[32])(sbuf + 16 * C_);
        #pragma unroll
        for (int i = 0; i < 16; ++i) {
            int idx = tt + i * 128;
            int rr = idx >> 8, cc = idx & 255;
            qs[half * 8 + rr][cc] = query[(size_t)(rb + rr) * C_ + cc];
        }
        __syncthreads();
        if (tt < 64) {
            float acc[8] = {0.f, 0.f, 0.f, 0.f, 0.f, 0.f, 0.f, 0.f};
            for (int k4 = 0; k4 < C_ / 4; ++k4) {
                int k = k4 * 4;
                float w0 = Wo[(k + 0) * 64 + tt], w1 = Wo[(k + 1) * 64 + tt];
                float w2 = Wo[(k + 2) * 64 + tt], w3 = Wo[(k + 3) * 64 + tt];
                #pragma unroll
                for (int r = 0; r < 8; ++r) {
                    const float4 qv = *(reinterpret_cast<const float4*>(qs[half * 8 + r]) + k4);
                    acc[r] = __builtin_fmaf(qv.x, w0, acc[r]);
                    acc[r] = __builtin_fmaf(qv.y, w1, acc[r]);
                    acc[r] = __builtin_fmaf(qv.z, w2, acc[r]);
                    acc[r] = __builtin_fmaf(qv.w, w3, acc[r]);
                }
            }
            float b = bo[tt];
            float nrm = (tt & 1) ? 23.0f : 46.0f;
            #pragma unroll
            for (int r = 0; r < 8; ++r) offn[(size_t)(rb + r) * 64 + tt] = (acc[r] + b) / nrm;
        } else {
            // Wa wave, lane-split (R12): lanes 0-31 rows 0-3, lanes 32-63 rows 4-7
            int u = tt - 64;
            int j = u & 31;
            int rbase = (u >> 5) * 4;
            float acc[4] = {0.f, 0.f, 0.f, 0.f};
            for (int k4 = 0; k4 < C_ / 4; ++k4) {
                int k = k4 * 4;
                float w0 = Wa[(k + 0) * 32 + j], w1 = Wa[(k + 1) * 32 + j];
                float w2 = Wa[(k + 2) * 32 + j], w3 = Wa[(k + 3) * 32 + j];
                #pragma unroll
                for (int r = 0; r < 4; ++r) {
                    const float4 qv = *(reinterpret_cast<const float4*>(qs[half * 8 + rbase + r]) + k4);
                    acc[r] = __builtin_fmaf(qv.x, w0, acc[r]);
                    acc[r] = __builtin_fmaf(qv.y, w1, acc[r]);
                    acc[r] = __builtin_fmaf(qv.z, w2, acc[r]);
                    acc[r] = __builtin_fmaf(qv.w, w3, acc[r]);
                }
            }
            float b = ba[j];
            #pragma unroll
            for (int r = 0; r < 4; ++r) lg[half * 8 + rbase + r][j] = acc[r] + b;
        }
        __syncthreads();
        if (tt < 64) {
            int r = tt >> 3, h = tt & 7;
            int lr = half * 8 + r;
            float v0 = lg[lr][h * 4 + 0], v1 = lg[lr][h * 4 + 1];
            float v2 = lg[lr][h * 4 + 2], v3 = lg[lr][h * 4 + 3];
            float m = fmaxf(fmaxf(fmaxf(v0, v1), v2), v3);
            float e0 = expf(v0 - m), e1 = expf(v1 - m), e2 = expf(v2 - m), e3 = expf(v3 - m);
            float s = ((e0 + e1) + e2) + e3;
            attn[(size_t)(rb + r) * 32 + h * 4 + 0] = e0 / s;
            attn[(size_t)(rb + r) * 32 + h * 4 + 1] = e1 / s;
            attn[(size_t)(rb + r) * 32 + h * 4 + 2] = e2 / s;
            attn[(size_t)(rb + r) * 32 + h * 4 + 3] = e3 / s;
        }
    }
}

// ---------------- fused: f32 gap-tested logits (quad S32Q, 1x16B load) + hfma2 sampling + epilogue prefetch ----------------
__global__ void __launch_bounds__(256) fused_kernel(
        const ushort_t* __restrict__ VW, const float* __restrict__ offn,
        const float* __restrict__ attn, const float* __restrict__ grd_col,
        const float* __restrict__ grd_row, const float* __restrict__ S32Q,
        const float* __restrict__ query, const float* __restrict__ bout,
        float* __restrict__ out, float* __restrict__ amax_out,
        int* __restrict__ cnt, int* __restrict__ list) {
    int bid = blockIdx.x;
    int row = ((bid & 7) << 12) | (bid >> 3);   // XCD-bijective: batch <-> XCD affinity
    int b = row >> 12;
    int q = row & (NQ - 1);
    int t = threadIdx.x;
    __shared__ __align__(16) int     g_ip[256][4];
    __shared__ __align__(16) __half2 g_wh[256][4];   // duplicated half2 per corner weight
    __shared__ __align__(16) float red[NV][C_];
    __shared__ float logits_sh[NV];
    __shared__ float wf_sh[NV];

    // epilogue prefetch: issue early so L2/HBM latency hides under phases A/B
    float q_pre = query[(size_t)row * C_ + t];
    float b_pre = bout[t];

    // ---- phase A (f32): t = v*32 + (h*4+p)
    {
        int v = t >> 5, r = t & 31, h = r >> 2;
        const float2 off2 = ((const float2*)(offn + (size_t)row * 64))[r];
        float at = attn[(size_t)row * 32 + r];
        float refx = grd_col[q * NV + v];
        float refy = grd_row[q * NV + v];
        float lx = refx + off2.x;
        float ly = refy + off2.y;
        float x = lx * 46.0f - 0.5f;
        float y = ly * 23.0f - 0.5f;
        float x0f = floorf(x), y0f = floorf(y);
        float wx1 = x - x0f, wy1 = y - y0f;
        float wx0 = 1.0f - wx1, wy0 = 1.0f - wy1;
        int xi = (int)x0f, yi = (int)y0f;
        bool vx0 = (x0f >= 0.0f) && (x0f < 46.0f);
        bool vx1 = (x0f + 1.0f >= 0.0f) && (x0f + 1.0f < 46.0f);
        bool vy0 = (y0f >= 0.0f) && (y0f < 23.0f);
        bool vy1 = (y0f + 1.0f >= 0.0f) && (y0f + 1.0f < 23.0f);
        int xc0 = min(max(xi, 0), WV - 1), xc1 = min(max(xi + 1, 0), WV - 1);
        int yc0 = min(max(yi, 0), HV - 1), yc1 = min(max(yi + 1, 0), HV - 1);
        float w00 = (vx0 && vy0) ? wx0 * wy0 : 0.0f;
        float w10 = (vx1 && vy0) ? wx1 * wy0 : 0.0f;
        float w01 = (vx0 && vy1) ? wx0 * wy1 : 0.0f;
        float w11 = (vx1 && vy1) ? wx1 * wy1 : 0.0f;
        int ip00 = yc0 * WV + xc0, ip10 = yc0 * WV + xc1;
        int ip01 = yc1 * WV + xc0, ip11 = yc1 * WV + xc1;

        g_ip[t][0] = ip00 * (C_ * 2); g_ip[t][1] = ip10 * (C_ * 2);   // byte offsets
        g_ip[t][2] = ip01 * (C_ * 2); g_ip[t][3] = ip11 * (C_ * 2);
        __half hw0 = __float2half(w00 * at);
        __half hw1 = __float2half(w10 * at);
        __half hw2 = __float2half(w01 * at);
        __half hw3 = __float2half(w11 * at);
        g_wh[t][0] = __halves2half2(hw0, hw0);
        g_wh[t][1] = __halves2half2(hw1, hw1);
        g_wh[t][2] = __halves2half2(hw2, hw2);
        g_wh[t][3] = __halves2half2(hw3, hw3);

        // quad S32 load: slot[ip] = (S[ip], S[ip+1], S[ip+WV], S[ip+WV+1])
        const float4* Sb = (const float4*)S32Q + (size_t)b * NPIX * HEADS;
        float4 sq = Sb[ip00 * HEADS + h];
        float s10 = (ip10 == ip00) ? sq.x : sq.y;
        float s01 = (ip01 == ip00) ? sq.x : sq.z;
        float hi0 = (ip01 == ip00) ? sq.y : sq.w;
        float s11 = (ip11 == ip01) ? s01 : hi0;
        float samp = w00 * sq.x + w10 * s10 + w01 * s01 + w11 * s11;
        float contrib = at * samp;
        #pragma unroll
        for (int s2 = 16; s2; s2 >>= 1) contrib += __shfl_down(contrib, s2, 32);
        if (r == 0) logits_sh[v] = contrib;
    }
    __syncthreads();                                   // barrier 1 (A -> B)

    // ---- lanes 0..7 (f32): argmax + gap test + softmax weights
    if (t < 8) {
        float m = logits_sh[0]; int am = 0;
        #pragma unroll
        for (int v2 = 1; v2 < NV; ++v2) {
            float lv = logits_sh[v2];
            if (lv > m) { m = lv; am = v2; }
        }
        float e = expf(logits_sh[t] - m);
        float ssum = e;
        ssum += __shfl_xor(ssum, 1, 8);
        ssum += __shfl_xor(ssum, 2, 8);
        ssum += __shfl_xor(ssum, 4, 8);
        wf_sh[t] = e / ssum;
        if (t == 0) {
            amax_out[row] = (float)am;
            float m2 = -1e30f;
            #pragma unroll
            for (int v2 = 0; v2 < NV; ++v2) {
                float lv = logits_sh[v2];
                if (v2 != am && lv > m2) m2 = lv;
            }
            float thr = 1e-4f * fmaxf(1.0f, fabsf(m));
            if ((m - m2) < thr) {
                int idx = atomicAdd(cnt, 1);
                list[idx] = row;
            }
        }
    }

    // ---- phase B: 8 groups x 32 threads; group g = v; 8 channels/thread; packed f16 FMA
    {
        int g = t >> 5, lt = t & 31;
        int c0 = lt * 8;
        int c2 = c0 * 2;               // channel byte offset
        int hb = lt >> 2;
        const char* vb = (const char*)(VW + (size_t)b * NPIX * C_);
        __half2 h01 = __float2half2_rn(0.f);
        __half2 h23 = h01, h45 = h01, h67 = h01;
        #pragma unroll
        for (int pp = 0; pp < 2; ++pp) {
            int e0 = g * 32 + hb * 4 + pp * 2;         // entry (v=g, h=hb, p=pp*2); +1 -> p+1
            const int4   ipA = *reinterpret_cast<const int4*>(g_ip[e0]);
            const uint4  whA = *reinterpret_cast<const uint4*>(g_wh[e0]);
            const int4   ipB = *reinterpret_cast<const int4*>(g_ip[e0 + 1]);
            const uint4  whB = *reinterpret_cast<const uint4*>(g_wh[e0 + 1]);
            const uint4 uA0 = *reinterpret_cast<const uint4*>(vb + (ipA.x + c2));
            const uint4 uA1 = *reinterpret_cast<const uint4*>(vb + (ipA.y + c2));
            const uint4 uA2 = *reinterpret_cast<const uint4*>(vb + (ipA.z + c2));
            const uint4 uA3 = *reinterpret_cast<const uint4*>(vb + (ipA.w + c2));
            const uint4 uB0 = *reinterpret_cast<const uint4*>(vb + (ipB.x + c2));
            const uint4 uB1 = *reinterpret_cast<const uint4*>(vb + (ipB.y + c2));
            const uint4 uB2 = *reinterpret_cast<const uint4*>(vb + (ipB.z + c2));
            const uint4 uB3 = *reinterpret_cast<const uint4*>(vb + (ipB.w + c2));
            #define CORNER(WHU, U) { \
                const __half2 wh = *reinterpret_cast<const __half2*>(&WHU); \
                h01 = __hfma2(wh, *reinterpret_cast<const __half2*>(&U.x), h01); \
                h23 = __hfma2(wh, *reinterpret_cast<const __half2*>(&U.y), h23); \
                h45 = __hfma2(wh, *reinterpret_cast<const __half2*>(&U.z), h45); \
                h67 = __hfma2(wh, *reinterpret_cast<const __half2*>(&U.w), h67); }
            CORNER(whA.x, uA0)
            CORNER(whA.y, uA1)
            CORNER(whA.z, uA2)
            CORNER(whA.w, uA3)
            CORNER(whB.x, uB0)
            CORNER(whB.y, uB1)
            CORNER(whB.z, uB2)
            CORNER(whB.w, uB3)
            #undef CORNER
        }
        float a0 = __low2float(h01), a1 = __high2float(h01);
        float a2 = __low2float(h23), a3 = __high2float(h23);
        float a4 = __low2float(h45), a5 = __high2float(h45);
        float a6 = __low2float(h67), a7 = __high2float(h67);
        float4 s0v = {a0, a1, a2, a3}, s1v = {a4, a5, a6, a7};
        *reinterpret_cast<float4*>(&red[g][c0])     = s0v;
        *reinterpret_cast<float4*>(&red[g][c0 + 4]) = s1v;
    }
    __syncthreads();                                   // barrier 2 (B -> epilogue)
    float O = 0.f;
    #pragma unroll
    for (int g8 = 0; g8 < NV; ++g8) O = fmaf(wf_sh[g8], red[g8][t], O);
    out[(size_t)row * C_ + t] = O + b_pre + 2.0f * q_pre;
}

// ---------------- exact replication (compacted: grid-stride over flagged list) ----------------
__global__ void __launch_bounds__(256) exact_kernel(
        const float* __restrict__ v2d, const float* __restrict__ offn,
        const float* __restrict__ attn, const float* __restrict__ grd_col,
        const float* __restrict__ grd_row, const float* __restrict__ Wout,
        const float* __restrict__ bout, const float* __restrict__ Wp,
        const float* __restrict__ bp, const float* __restrict__ query,
        const int* __restrict__ cnt, const int* __restrict__ list,
        float* __restrict__ amax_out) {
#pragma clang fp contract(off)
    int n = *cnt;
    int t = threadIdx.x;
    int h = t >> 5;
    __shared__ float s_off[64];
    __shared__ float s_attn[32];
    __shared__ float wp_lds[C_];
    __shared__ float out_l[NV][C_ + 1];
    __shared__ float bevs_l[NV][C_ + 1];
    __shared__ float lgs[NV];
    wp_lds[t] = Wp[t];

    for (int i = blockIdx.x; i < n; i += gridDim.x) {
        int row = list[i];
        int b = row >> 12;
        int q = row & (NQ - 1);
        if (t < 64)      s_off[t]       = offn[(size_t)row * 64 + t];
        else if (t < 96) s_attn[t - 64] = attn[(size_t)row * 32 + (t - 64)];
        __syncthreads();

        const float* vb = v2d + (size_t)b * NPIX * C_;
        #pragma unroll
        for (int v = 0; v < NV; ++v) {
            float refx = grd_col[q * NV + v];
            float refy = grd_row[q * NV + v];
            float acc = 0.0f;
            #pragma unroll
            for (int p = 0; p < PTS; ++p) {
                float lx = refx + s_off[h * 8 + p * 2 + 0];
                float ly = refy + s_off[h * 8 + p * 2 + 1];
                float x = lx * 46.0f - 0.5f;
                float y = ly * 23.0f - 0.5f;
                float x0f = floorf(x), y0f = floorf(y);
                float wx1 = x - x0f, wy1 = y - y0f;
                float wx0 = 1.0f - wx1, wy0 = 1.0f - wy1;
                int xi = (int)x0f, yi = (int)y0f;
                bool vx0 = (x0f >= 0.0f) && (x0f < 46.0f);
                bool vx1 = (x0f + 1.0f >= 0.0f) && (x0f + 1.0f < 46.0f);
                bool vy0 = (y0f >= 0.0f) && (y0f < 23.0f);
                bool vy1 = (y0f + 1.0f >= 0.0f) && (y0f + 1.0f < 23.0f);
                int xc0 = min(max(xi, 0), WV - 1), xc1 = min(max(xi + 1, 0), WV - 1);
                int yc0 = min(max(yi, 0), HV - 1), yc1 = min(max(yi + 1, 0), HV - 1);
                float g00 = (vx0 && vy0) ? vb[(yc0 * WV + xc0) * C_ + t] : 0.0f;
                float g10 = (vx1 && vy0) ? vb[(yc0 * WV + xc1) * C_ + t] : 0.0f;
                float g01 = (vx0 && vy1) ? vb[(yc1 * WV + xc0) * C_ + t] : 0.0f;
                float g11 = (vx1 && vy1) ? vb[(yc1 * WV + xc1) * C_ + t] : 0.0f;
                float t00 = g00 * (wx0 * wy0);
                float t10 = g10 * (wx1 * wy0);
                float t01 = g01 * (wx0 * wy1);
                float t11 = g11 * (wx1 * wy1);
                float samp = ((t00 + t10) + t01) + t11;
                float pr = s_attn[h * 4 + p] * samp;
                acc = acc + pr;
            }
            out_l[v][t] = acc;
        }
        __syncthreads();

        float bacc[NV];
        #pragma unroll
        for (int v = 0; v < NV; ++v) bacc[v] = 0.f;
        for (int i2 = 0; i2 < C_; ++i2) {
            float w_it = Wout[i2 * C_ + t];
            #pragma unroll
            for (int v = 0; v < NV; ++v) bacc[v] = __builtin_fmaf(out_l[v][i2], w_it, bacc[v]);
        }
        float bo_t = bout[t];
        float qv = query[(size_t)row * C_ + t];
        #pragma unroll
        for (int v = 0; v < NV; ++v) bevs_l[v][t] = (bacc[v] + bo_t) + qv;
        __syncthreads();

        if (t < NV) {
            float lv = 0.f;
            for (int c = 0; c < C_; ++c) lv = __builtin_fmaf(bevs_l[t][c], wp_lds[c], lv);
            lgs[t] = lv + bp[0];
        }
        __syncthreads();

        if (t == 0) {
            float l[NV];
            #pragma unroll
            for (int v = 0; v < NV; ++v) l[v] = lgs[v];
            float m = l[0];
            #pragma unroll
            for (int v = 1; v < NV; ++v) m = fmaxf(m, l[v]);
            float e[NV];
            #pragma unroll
            for (int v = 0; v < NV; ++v) e[v] = expf(l[v] - m);
            float s = ((e[0] + e[1]) + (e[2] + e[3])) + ((e[4] + e[5]) + (e[6] + e[7]));
            float w[NV];
            #pragma unroll
            for (int v = 0; v < NV; ++v) w[v] = e[v] / s;
            int am = 0; float wm = w[0];
            #pragma unroll
            for (int v = 1; v < NV; ++v) { if (w[v] > wm) { wm = w[v]; am = v; } }
            amax_out[row] = (float)am;
        }
        __syncthreads();
    }
}

extern "C" void kernel_launch(void* const* d_in, const int* in_sizes, int n_in,
                              void* d_out, int out_size, void* d_ws, size_t ws_size,
                              hipStream_t stream) {
    const float* query   = (const float*)d_in[0];
    const float* value   = (const float*)d_in[1];
    const float* grd_col = (const float*)d_in[2];
    const float* grd_row = (const float*)d_in[3];
    const float* Wv      = (const float*)d_in[4];
    const float* bv      = (const float*)d_in[5];
    const float* Wo      = (const float*)d_in[6];
    const float* bo      = (const float*)d_in[7];
    const float* Wa      = (const float*)d_in[8];
    const float* ba      = (const float*)d_in[9];
    const float* Wout    = (const float*)d_in[10];
    const float* bout    = (const float*)d_in[11];
    const float* Wp      = (const float*)d_in[12];
    const float* bp      = (const float*)d_in[13];

    float* out  = (float*)d_out;
    float* ws   = (float*)d_ws;
    float* offn = ws;                                        // 32768*64 f32
    float* attn = offn + (size_t)NROW * 64;                  // 32768*32 f32
    float* v2d  = attn + (size_t)NROW * 32;                  // 8464*256 f32
    float* wp2f = v2d + (size_t)BS * NPIX * C_;              // 256 f32
    float* S32Q = wp2f + C_;                                 // 8464*8 float4 = 270848 f32
    int* cnt    = (int*)(S32Q + (size_t)BS * NPIX * HEADS * 4); // 1 int (padded to 4)
    int* list   = cnt + 4;                                   // 32768 int
    ushort_t* VW = (ushort_t*)(list + NROW);                 // 8464*256 fp16
    float* WvWout = (float*)(VW + (size_t)BS * NPIX * C_);   // 256*256 f32
    float* bvW    = WvWout + C_ * C_;                        // 256 f32
    float* amax = out + (size_t)NROW * C_;

    prep_kernel<<<65, 256, 0, stream>>>(Wout, Wp, Wv, bv, WvWout, wp2f, bvW, cnt);
    proj_kernel<<<NVBLK2 + NQBLK, 256, 0, stream>>>(value, Wv, bv, WvWout, bvW, wp2f,
                                                    query, Wo, bo, Wa, ba,
                                                    v2d, VW, S32Q, offn, attn);
    fused_kernel<<<NROW, 256, 0, stream>>>(VW, offn, attn, grd_col, grd_row, S32Q,
                                           query, bout, out, amax, cnt, list);
    exact_kernel<<<512, 256, 0, stream>>>(v2d, offn, attn, grd_col, grd_row,
                                          Wout, bout, Wp, bp, query, cnt, list, amax);
}